// Round 1
// baseline (867.644 us; speedup 1.0000x reference)
//
#include <hip/hip_runtime.h>

#define NF 128

// ---------------- init / normalize ----------------

__global__ __launch_bounds__(256) void k_init_deg(float* __restrict__ deg, int n) {
  int i = blockIdx.x * 256 + threadIdx.x;
  if (i < n) deg[i] = 1.0f;  // self-loop weight
}

__global__ __launch_bounds__(256) void k_rownorm(const float* __restrict__ feat,
                                                 float* __restrict__ xn, int n) {
  int gid = blockIdx.x * 256 + threadIdx.x;
  int wave = gid >> 6, lane = gid & 63;
  if (wave >= n) return;
  float2 v = ((const float2*)(feat + (size_t)wave * NF))[lane];
  float s = v.x + v.y;
#pragma unroll
  for (int off = 1; off < 64; off <<= 1) s += __shfl_xor(s, off, 64);
  float inv = 1.0f / s;
  float2 o = {v.x * inv, v.y * inv};
  ((float2*)(xn + (size_t)wave * NF))[lane] = o;
}

// ---------------- degree + counts ----------------

__global__ __launch_bounds__(256) void k_edge_pass1(const int* __restrict__ col,
                                                    const float* __restrict__ w,
                                                    float* __restrict__ deg,
                                                    int* __restrict__ cnt, int ne) {
  int e = blockIdx.x * 256 + threadIdx.x;
  if (e >= ne) return;
  int c = col[e];
  atomicAdd(&deg[c], w[e]);
  atomicAdd(&cnt[c], 1);
}

__global__ __launch_bounds__(256) void k_dinv(float* __restrict__ deg, int n) {
  int i = blockIdx.x * 256 + threadIdx.x;
  if (i < n) deg[i] = rsqrtf(deg[i]);  // deg >= 1 always
}

// ---------------- exclusive scan (3-kernel), 1024 items/block ----------------

__global__ __launch_bounds__(256) void k_scan_local(const int* __restrict__ cnt,
                                                    int* __restrict__ excl,
                                                    int* __restrict__ bsum, int n) {
  __shared__ int sd[256];
  int tid = threadIdx.x;
  int idx = blockIdx.x * 1024 + tid * 4;
  int4 v = {0, 0, 0, 0};
  if (idx + 4 <= n) {
    v = *(const int4*)&cnt[idx];
  } else {
    if (idx < n)     v.x = cnt[idx];
    if (idx + 1 < n) v.y = cnt[idx + 1];
    if (idx + 2 < n) v.z = cnt[idx + 2];
    if (idx + 3 < n) v.w = cnt[idx + 3];
  }
  int tsum = v.x + v.y + v.z + v.w;
  sd[tid] = tsum;
  __syncthreads();
  for (int off = 1; off < 256; off <<= 1) {
    int t = (tid >= off) ? sd[tid - off] : 0;
    __syncthreads();
    sd[tid] += t;
    __syncthreads();
  }
  int texcl = sd[tid] - tsum;
  if (tid == 255) bsum[blockIdx.x] = sd[255];
  int4 w;
  w.x = texcl; w.y = texcl + v.x; w.z = texcl + v.x + v.y; w.w = texcl + v.x + v.y + v.z;
  if (idx + 4 <= n) {
    *(int4*)&excl[idx] = w;
  } else {
    if (idx < n)     excl[idx] = w.x;
    if (idx + 1 < n) excl[idx + 1] = w.y;
    if (idx + 2 < n) excl[idx + 2] = w.z;
    if (idx + 3 < n) excl[idx + 3] = w.w;
  }
}

__global__ __launch_bounds__(256) void k_scan_sums(const int* __restrict__ bsum,
                                                   int* __restrict__ bexcl,
                                                   int* __restrict__ rowptr_end, int nb) {
  __shared__ int sd[256];
  int tid = threadIdx.x;
  int v = (tid < nb) ? bsum[tid] : 0;
  sd[tid] = v;
  __syncthreads();
  for (int off = 1; off < 256; off <<= 1) {
    int t = (tid >= off) ? sd[tid - off] : 0;
    __syncthreads();
    sd[tid] += t;
    __syncthreads();
  }
  if (tid < nb) bexcl[tid] = sd[tid] - v;
  if (tid == 255) rowptr_end[0] = sd[255];
}

__global__ __launch_bounds__(256) void k_scan_add(int* __restrict__ rowptr,
                                                  int* __restrict__ cursor,
                                                  const int* __restrict__ bexcl, int n) {
  int i = blockIdx.x * 256 + threadIdx.x;
  if (i >= n) return;
  int v = rowptr[i] + bexcl[i >> 10];
  rowptr[i] = v;
  cursor[i] = v;
}

// ---------------- CSC scatter ----------------

__global__ __launch_bounds__(256) void k_edge_scatter(const int* __restrict__ row,
                                                      const int* __restrict__ col,
                                                      const float* __restrict__ w,
                                                      const float* __restrict__ dinv,
                                                      int* __restrict__ cursor,
                                                      int* __restrict__ sRow,
                                                      float* __restrict__ sNorm, int ne) {
  int e = blockIdx.x * 256 + threadIdx.x;
  if (e >= ne) return;
  int r = row[e], c = col[e];
  int pos = atomicAdd(&cursor[c], 1);
  sRow[pos] = r;
  sNorm[pos] = dinv[r] * w[e] * dinv[c];
}

// ---------------- GEMM: Y[n,128] = X[n,128] @ W[128,128] ----------------
// block 256, tile 64 rows; W fully in LDS; 4x8 register blocking per thread.

__global__ __launch_bounds__(256, 2) void k_gemm128(const float* __restrict__ X,
                                                    const float* __restrict__ W,
                                                    float* __restrict__ Y, int n) {
  __shared__ float Ws[128 * 128];
  __shared__ float Xs[64 * 36];  // padded stride 36 to dodge bank conflicts
  const int tid = threadIdx.x;
  for (int i = tid * 4; i < 128 * 128; i += 256 * 4)
    *(float4*)&Ws[i] = *(const float4*)&W[i];

  int r0 = blockIdx.x * 64;
  int tcol = tid & 15, trow = tid >> 4;
  float acc[4][8] = {};

  for (int kc = 0; kc < 128; kc += 32) {
    __syncthreads();
    {
      int rr = tid >> 2;            // 0..63
      int cc = (tid & 3) * 8;       // 0,8,16,24
      int grow = r0 + rr;
      if (grow >= n) grow = n - 1;  // clamp; stores are guarded
      const float* src = X + (size_t)grow * NF + kc + cc;
      float4 a = *(const float4*)src;
      float4 b = *(const float4*)(src + 4);
      *(float4*)&Xs[rr * 36 + cc] = a;
      *(float4*)&Xs[rr * 36 + cc + 4] = b;
    }
    __syncthreads();
#pragma unroll
    for (int k4 = 0; k4 < 32; k4 += 4) {
      float4 xv[4];
#pragma unroll
      for (int i = 0; i < 4; i++)
        xv[i] = *(const float4*)&Xs[(trow * 4 + i) * 36 + k4];
#pragma unroll
      for (int kk = 0; kk < 4; kk++) {
        float4 w0 = *(const float4*)&Ws[(kc + k4 + kk) * 128 + tcol * 4];
        float4 w1 = *(const float4*)&Ws[(kc + k4 + kk) * 128 + 64 + tcol * 4];
#pragma unroll
        for (int i = 0; i < 4; i++) {
          float xx = ((const float*)&xv[i])[kk];
          acc[i][0] = fmaf(xx, w0.x, acc[i][0]);
          acc[i][1] = fmaf(xx, w0.y, acc[i][1]);
          acc[i][2] = fmaf(xx, w0.z, acc[i][2]);
          acc[i][3] = fmaf(xx, w0.w, acc[i][3]);
          acc[i][4] = fmaf(xx, w1.x, acc[i][4]);
          acc[i][5] = fmaf(xx, w1.y, acc[i][5]);
          acc[i][6] = fmaf(xx, w1.z, acc[i][6]);
          acc[i][7] = fmaf(xx, w1.w, acc[i][7]);
        }
      }
    }
  }
#pragma unroll
  for (int i = 0; i < 4; i++) {
    int gr = r0 + trow * 4 + i;
    if (gr < n) {
      *(float4*)&Y[(size_t)gr * NF + tcol * 4] = *(float4*)&acc[i][0];
      *(float4*)&Y[(size_t)gr * NF + 64 + tcol * 4] = *(float4*)&acc[i][4];
    }
  }
}

// ---------------- pull aggregation, H=128: one wave per node ----------------

__global__ __launch_bounds__(256) void k_agg128(const float* __restrict__ XP,
                                                const int* __restrict__ rowptr,
                                                const int* __restrict__ sRow,
                                                const float* __restrict__ sNorm,
                                                const float* __restrict__ dinv,
                                                const float* __restrict__ bias,
                                                float* __restrict__ Y, int n, int relu) {
  int gid = blockIdx.x * 256 + threadIdx.x;
  int i = gid >> 6, lane = gid & 63;
  if (i >= n) return;
  float di = dinv[i];
  float sn = di * di;
  float2 xv = ((const float2*)(XP + (size_t)i * NF))[lane];
  float ax = xv.x * sn, ay = xv.y * sn;
  int s = rowptr[i], e = rowptr[i + 1];
  for (int j = s; j < e; ++j) {
    int r = sRow[j];
    float nr = sNorm[j];
    float2 v = ((const float2*)(XP + (size_t)r * NF))[lane];
    ax = fmaf(v.x, nr, ax);
    ay = fmaf(v.y, nr, ay);
  }
  float2 b = ((const float2*)bias)[lane];
  ax += b.x; ay += b.y;
  if (relu) { ax = fmaxf(ax, 0.f); ay = fmaxf(ay, 0.f); }
  float2 o = {ax, ay};
  ((float2*)(Y + (size_t)i * NF))[lane] = o;
}

// ---------------- layer 2: GEMV (H=1) + scalar aggregation ----------------

__global__ __launch_bounds__(256) void k_gemv(const float* __restrict__ X,
                                              const float* __restrict__ w2,
                                              float* __restrict__ y, int n) {
  int gid = blockIdx.x * 256 + threadIdx.x;
  int i = gid >> 6, lane = gid & 63;
  if (i >= n) return;
  float2 x = ((const float2*)(X + (size_t)i * NF))[lane];
  float2 w = ((const float2*)w2)[lane];
  float s = x.x * w.x + x.y * w.y;
#pragma unroll
  for (int off = 1; off < 64; off <<= 1) s += __shfl_xor(s, off, 64);
  if (lane == 0) y[i] = s;
}

__global__ __launch_bounds__(256) void k_agg1(const float* __restrict__ xp2,
                                              const int* __restrict__ rowptr,
                                              const int* __restrict__ sRow,
                                              const float* __restrict__ sNorm,
                                              const float* __restrict__ dinv,
                                              const float* __restrict__ b2,
                                              float* __restrict__ out, int n) {
  int i = blockIdx.x * 256 + threadIdx.x;
  if (i >= n) return;
  float di = dinv[i];
  float acc = xp2[i] * di * di;
  int s = rowptr[i], e = rowptr[i + 1];
  for (int j = s; j < e; ++j) acc = fmaf(xp2[sRow[j]], sNorm[j], acc);
  out[i] = acc + b2[0];
}

// ---------------- launch ----------------

extern "C" void kernel_launch(void* const* d_in, const int* in_sizes, int n_in,
                              void* d_out, int out_size, void* d_ws, size_t ws_size,
                              hipStream_t stream) {
  const float* feat = (const float*)d_in[0];
  const int* ei = (const int*)d_in[1];
  const float* ew = (const float*)d_in[2];
  const float* W0 = (const float*)d_in[3];
  const float* b0 = (const float*)d_in[4];
  const float* W1 = (const float*)d_in[5];
  const float* b1 = (const float*)d_in[6];
  const float* W2 = (const float*)d_in[7];
  const float* b2 = (const float*)d_in[8];
  float* out = (float*)d_out;

  const int N_ = in_sizes[0] / NF;
  const int E_ = in_sizes[2];
  const int* row = ei;
  const int* col = ei + E_;

  char* ws = (char*)d_ws;
  size_t off = 0;
  auto alloc = [&](size_t bytes) -> void* {
    void* p = ws + off;
    off = (off + bytes + 255) & ~(size_t)255;
    return p;
  };
  float* bufA  = (float*)alloc((size_t)N_ * NF * 4);
  float* bufB  = (float*)alloc((size_t)N_ * NF * 4);
  float* deg   = (float*)alloc((size_t)N_ * 4);        // becomes dinv in place
  int*   rowptr= (int*)  alloc(((size_t)N_ + 1) * 4);
  int*   cursor= (int*)  alloc((size_t)N_ * 4);
  int*   cnt   = (int*)  alloc((size_t)N_ * 4);
  int*   bsum  = (int*)  alloc(256 * 4);
  int*   bexcl = (int*)  alloc(256 * 4);
  int*   sRow  = (int*)  alloc((size_t)E_ * 4);
  float* sNorm = (float*)alloc((size_t)E_ * 4);
  float* xp2   = (float*)alloc((size_t)N_ * 4);

  const int nThreads = 256;
  const int gN   = (N_ + nThreads - 1) / nThreads;
  const int gE   = (E_ + nThreads - 1) / nThreads;
  const int gWav = (N_ + 3) / 4;               // one wave (64 lanes) per node
  const int nScanBlocks = (N_ + 1023) / 1024;  // <= 256 required

  hipMemsetAsync(cnt, 0, (size_t)N_ * 4, stream);
  k_init_deg<<<gN, nThreads, 0, stream>>>(deg, N_);
  k_rownorm<<<gWav, nThreads, 0, stream>>>(feat, bufA, N_);
  k_edge_pass1<<<gE, nThreads, 0, stream>>>(col, ew, deg, cnt, E_);
  k_dinv<<<gN, nThreads, 0, stream>>>(deg, N_);
  k_scan_local<<<nScanBlocks, nThreads, 0, stream>>>(cnt, rowptr, bsum, N_);
  k_scan_sums<<<1, nThreads, 0, stream>>>(bsum, bexcl, rowptr + N_, nScanBlocks);
  k_scan_add<<<gN, nThreads, 0, stream>>>(rowptr, cursor, bexcl, N_);
  k_edge_scatter<<<gE, nThreads, 0, stream>>>(row, col, ew, deg, cursor, sRow, sNorm, E_);

  const int gGemm = (N_ + 63) / 64;
  // layer 0
  k_gemm128<<<gGemm, nThreads, 0, stream>>>(bufA, W0, bufB, N_);
  k_agg128<<<gWav, nThreads, 0, stream>>>(bufB, rowptr, sRow, sNorm, deg, b0, bufA, N_, 1);
  // layer 1
  k_gemm128<<<gGemm, nThreads, 0, stream>>>(bufA, W1, bufB, N_);
  k_agg128<<<gWav, nThreads, 0, stream>>>(bufB, rowptr, sRow, sNorm, deg, b1, bufA, N_, 1);
  // layer 2
  k_gemv<<<gWav, nThreads, 0, stream>>>(bufA, W2, xp2, N_);
  k_agg1<<<gN, nThreads, 0, stream>>>(xp2, rowptr, sRow, sNorm, deg, b2, out, N_);
}

// Round 3
// 753.936 us; speedup vs baseline: 1.1508x; 1.1508x over previous
//
#include <hip/hip_runtime.h>

#define NF 128

// ---------------- init / normalize ----------------

__global__ __launch_bounds__(256) void k_init_deg(float* __restrict__ deg, int n) {
  int i = blockIdx.x * 256 + threadIdx.x;
  if (i < n) deg[i] = 1.0f;  // self-loop weight
}

__global__ __launch_bounds__(256) void k_rownorm(const float* __restrict__ feat,
                                                 float* __restrict__ xn, int n) {
  int gid = blockIdx.x * 256 + threadIdx.x;
  int wave = gid >> 6, lane = gid & 63;
  if (wave >= n) return;
  float2 v = ((const float2*)(feat + (size_t)wave * NF))[lane];
  float s = v.x + v.y;
#pragma unroll
  for (int off = 1; off < 64; off <<= 1) s += __shfl_xor(s, off, 64);
  float inv = 1.0f / s;
  float2 o = {v.x * inv, v.y * inv};
  ((float2*)(xn + (size_t)wave * NF))[lane] = o;
}

// ---------------- degree + counts ----------------

__global__ __launch_bounds__(256) void k_edge_pass1(const int* __restrict__ col,
                                                    const float* __restrict__ w,
                                                    float* __restrict__ deg,
                                                    int* __restrict__ cnt, int ne) {
  int e = blockIdx.x * 256 + threadIdx.x;
  if (e >= ne) return;
  int c = col[e];
  atomicAdd(&deg[c], w[e]);
  atomicAdd(&cnt[c], 1);
}

__global__ __launch_bounds__(256) void k_dinv(float* __restrict__ deg, int n) {
  int i = blockIdx.x * 256 + threadIdx.x;
  if (i < n) deg[i] = rsqrtf(deg[i]);  // deg >= 1 always
}

// ---------------- exclusive scan (3-kernel), 1024 items/block ----------------

__global__ __launch_bounds__(256) void k_scan_local(const int* __restrict__ cnt,
                                                    int* __restrict__ excl,
                                                    int* __restrict__ bsum, int n) {
  __shared__ int sd[256];
  int tid = threadIdx.x;
  int idx = blockIdx.x * 1024 + tid * 4;
  int4 v = {0, 0, 0, 0};
  if (idx + 4 <= n) {
    v = *(const int4*)&cnt[idx];
  } else {
    if (idx < n)     v.x = cnt[idx];
    if (idx + 1 < n) v.y = cnt[idx + 1];
    if (idx + 2 < n) v.z = cnt[idx + 2];
    if (idx + 3 < n) v.w = cnt[idx + 3];
  }
  int tsum = v.x + v.y + v.z + v.w;
  sd[tid] = tsum;
  __syncthreads();
  for (int off = 1; off < 256; off <<= 1) {
    int t = (tid >= off) ? sd[tid - off] : 0;
    __syncthreads();
    sd[tid] += t;
    __syncthreads();
  }
  int texcl = sd[tid] - tsum;
  if (tid == 255) bsum[blockIdx.x] = sd[255];
  int4 w;
  w.x = texcl; w.y = texcl + v.x; w.z = texcl + v.x + v.y; w.w = texcl + v.x + v.y + v.z;
  if (idx + 4 <= n) {
    *(int4*)&excl[idx] = w;
  } else {
    if (idx < n)     excl[idx] = w.x;
    if (idx + 1 < n) excl[idx + 1] = w.y;
    if (idx + 2 < n) excl[idx + 2] = w.z;
    if (idx + 3 < n) excl[idx + 3] = w.w;
  }
}

__global__ __launch_bounds__(256) void k_scan_sums(const int* __restrict__ bsum,
                                                   int* __restrict__ bexcl,
                                                   int* __restrict__ rowptr_end, int nb) {
  __shared__ int sd[256];
  int tid = threadIdx.x;
  int v = (tid < nb) ? bsum[tid] : 0;
  sd[tid] = v;
  __syncthreads();
  for (int off = 1; off < 256; off <<= 1) {
    int t = (tid >= off) ? sd[tid - off] : 0;
    __syncthreads();
    sd[tid] += t;
    __syncthreads();
  }
  if (tid < nb) bexcl[tid] = sd[tid] - v;
  if (tid == 255) rowptr_end[0] = sd[255];
}

__global__ __launch_bounds__(256) void k_scan_add(int* __restrict__ rowptr,
                                                  int* __restrict__ cursor,
                                                  const int* __restrict__ bexcl, int n) {
  int i = blockIdx.x * 256 + threadIdx.x;
  if (i >= n) return;
  int v = rowptr[i] + bexcl[i >> 10];
  rowptr[i] = v;
  cursor[i] = v;
}

// ---------------- CSC scatter: packed (row, norm) per edge ----------------

__global__ __launch_bounds__(256) void k_edge_scatter(const int* __restrict__ row,
                                                      const int* __restrict__ col,
                                                      const float* __restrict__ w,
                                                      const float* __restrict__ dinv,
                                                      int* __restrict__ cursor,
                                                      int2* __restrict__ sEdge, int ne) {
  int e = blockIdx.x * 256 + threadIdx.x;
  if (e >= ne) return;
  int r = row[e], c = col[e];
  int pos = atomicAdd(&cursor[c], 1);
  float nrm = dinv[r] * w[e] * dinv[c];
  sEdge[pos] = make_int2(r, __float_as_int(nrm));
}

// ---------------- GEMM: Y[n,128] = X[n,128] @ W[128,128] ----------------

__global__ __launch_bounds__(256, 2) void k_gemm128(const float* __restrict__ X,
                                                    const float* __restrict__ W,
                                                    float* __restrict__ Y, int n) {
  __shared__ float Ws[128 * 128];
  __shared__ float Xs[64 * 36];
  const int tid = threadIdx.x;
  for (int i = tid * 4; i < 128 * 128; i += 256 * 4)
    *(float4*)&Ws[i] = *(const float4*)&W[i];

  int r0 = blockIdx.x * 64;
  int tcol = tid & 15, trow = tid >> 4;
  float acc[4][8] = {};

  for (int kc = 0; kc < 128; kc += 32) {
    __syncthreads();
    {
      int rr = tid >> 2;
      int cc = (tid & 3) * 8;
      int grow = r0 + rr;
      if (grow >= n) grow = n - 1;
      const float* src = X + (size_t)grow * NF + kc + cc;
      float4 a = *(const float4*)src;
      float4 b = *(const float4*)(src + 4);
      *(float4*)&Xs[rr * 36 + cc] = a;
      *(float4*)&Xs[rr * 36 + cc + 4] = b;
    }
    __syncthreads();
#pragma unroll
    for (int k4 = 0; k4 < 32; k4 += 4) {
      float4 xv[4];
#pragma unroll
      for (int i = 0; i < 4; i++)
        xv[i] = *(const float4*)&Xs[(trow * 4 + i) * 36 + k4];
#pragma unroll
      for (int kk = 0; kk < 4; kk++) {
        float4 w0 = *(const float4*)&Ws[(kc + k4 + kk) * 128 + tcol * 4];
        float4 w1 = *(const float4*)&Ws[(kc + k4 + kk) * 128 + 64 + tcol * 4];
#pragma unroll
        for (int i = 0; i < 4; i++) {
          float xx = ((const float*)&xv[i])[kk];
          acc[i][0] = fmaf(xx, w0.x, acc[i][0]);
          acc[i][1] = fmaf(xx, w0.y, acc[i][1]);
          acc[i][2] = fmaf(xx, w0.z, acc[i][2]);
          acc[i][3] = fmaf(xx, w0.w, acc[i][3]);
          acc[i][4] = fmaf(xx, w1.x, acc[i][4]);
          acc[i][5] = fmaf(xx, w1.y, acc[i][5]);
          acc[i][6] = fmaf(xx, w1.z, acc[i][6]);
          acc[i][7] = fmaf(xx, w1.w, acc[i][7]);
        }
      }
    }
  }
#pragma unroll
  for (int i = 0; i < 4; i++) {
    int gr = r0 + trow * 4 + i;
    if (gr < n) {
      *(float4*)&Y[(size_t)gr * NF + tcol * 4] = *(float4*)&acc[i][0];
      *(float4*)&Y[(size_t)gr * NF + 64 + tcol * 4] = *(float4*)&acc[i][4];
    }
  }
}

// ---------------- pull aggregation, H=128 ----------------
// 2 nodes per wave (half-wave = 32 lanes x float4 = 512B row); edge loop
// unrolled x4 -> 8 gathers in flight per wave for latency hiding.

__global__ __launch_bounds__(256) void k_agg128(const float* __restrict__ XP,
                                                const int* __restrict__ rowptr,
                                                const int2* __restrict__ sEdge,
                                                const float* __restrict__ dinv,
                                                const float* __restrict__ bias,
                                                float* __restrict__ Y, int n, int relu) {
  int gid = blockIdx.x * 256 + threadIdx.x;
  int i = gid >> 5;           // node = half-wave id
  int lane = gid & 31;        // float4 slice of the 128-wide row
  if (i >= n) return;
  float di = dinv[i];
  float sn = di * di;
  float4 xv = ((const float4*)(XP + (size_t)i * NF))[lane];
  float4 acc = {xv.x * sn, xv.y * sn, xv.z * sn, xv.w * sn};
  int s = rowptr[i], e = rowptr[i + 1];
  int j = s;
  for (; j + 4 <= e; j += 4) {
    int2 e0 = sEdge[j], e1 = sEdge[j + 1], e2 = sEdge[j + 2], e3 = sEdge[j + 3];
    const float4* p0 = (const float4*)(XP + (size_t)e0.x * NF);
    const float4* p1 = (const float4*)(XP + (size_t)e1.x * NF);
    const float4* p2 = (const float4*)(XP + (size_t)e2.x * NF);
    const float4* p3 = (const float4*)(XP + (size_t)e3.x * NF);
    float4 v0 = p0[lane], v1 = p1[lane], v2 = p2[lane], v3 = p3[lane];
    float n0 = __int_as_float(e0.y), n1 = __int_as_float(e1.y);
    float n2 = __int_as_float(e2.y), n3 = __int_as_float(e3.y);
    acc.x = fmaf(v0.x, n0, acc.x); acc.y = fmaf(v0.y, n0, acc.y);
    acc.z = fmaf(v0.z, n0, acc.z); acc.w = fmaf(v0.w, n0, acc.w);
    acc.x = fmaf(v1.x, n1, acc.x); acc.y = fmaf(v1.y, n1, acc.y);
    acc.z = fmaf(v1.z, n1, acc.z); acc.w = fmaf(v1.w, n1, acc.w);
    acc.x = fmaf(v2.x, n2, acc.x); acc.y = fmaf(v2.y, n2, acc.y);
    acc.z = fmaf(v2.z, n2, acc.z); acc.w = fmaf(v2.w, n2, acc.w);
    acc.x = fmaf(v3.x, n3, acc.x); acc.y = fmaf(v3.y, n3, acc.y);
    acc.z = fmaf(v3.z, n3, acc.z); acc.w = fmaf(v3.w, n3, acc.w);
  }
  for (; j < e; ++j) {
    int2 ed = sEdge[j];
    float nr = __int_as_float(ed.y);
    float4 v = ((const float4*)(XP + (size_t)ed.x * NF))[lane];
    acc.x = fmaf(v.x, nr, acc.x); acc.y = fmaf(v.y, nr, acc.y);
    acc.z = fmaf(v.z, nr, acc.z); acc.w = fmaf(v.w, nr, acc.w);
  }
  float4 b = ((const float4*)bias)[lane];
  acc.x += b.x; acc.y += b.y; acc.z += b.z; acc.w += b.w;
  if (relu) {
    acc.x = fmaxf(acc.x, 0.f); acc.y = fmaxf(acc.y, 0.f);
    acc.z = fmaxf(acc.z, 0.f); acc.w = fmaxf(acc.w, 0.f);
  }
  ((float4*)(Y + (size_t)i * NF))[lane] = acc;
}

// ---------------- layer 2: GEMV (H=1) + scalar aggregation ----------------

__global__ __launch_bounds__(256) void k_gemv(const float* __restrict__ X,
                                              const float* __restrict__ w2,
                                              float* __restrict__ y, int n) {
  int gid = blockIdx.x * 256 + threadIdx.x;
  int i = gid >> 6, lane = gid & 63;
  if (i >= n) return;
  float2 x = ((const float2*)(X + (size_t)i * NF))[lane];
  float2 w = ((const float2*)w2)[lane];
  float s = x.x * w.x + x.y * w.y;
#pragma unroll
  for (int off = 1; off < 64; off <<= 1) s += __shfl_xor(s, off, 64);
  if (lane == 0) y[i] = s;
}

__global__ __launch_bounds__(256) void k_agg1(const float* __restrict__ xp2,
                                              const int* __restrict__ rowptr,
                                              const int2* __restrict__ sEdge,
                                              const float* __restrict__ dinv,
                                              const float* __restrict__ b2,
                                              float* __restrict__ out, int n) {
  int i = blockIdx.x * 256 + threadIdx.x;
  if (i >= n) return;
  float di = dinv[i];
  float acc = xp2[i] * di * di;
  int s = rowptr[i], e = rowptr[i + 1];
  int j = s;
  for (; j + 4 <= e; j += 4) {
    int2 e0 = sEdge[j], e1 = sEdge[j + 1], e2 = sEdge[j + 2], e3 = sEdge[j + 3];
    float v0 = xp2[e0.x], v1 = xp2[e1.x], v2 = xp2[e2.x], v3 = xp2[e3.x];
    acc = fmaf(v0, __int_as_float(e0.y), acc);
    acc = fmaf(v1, __int_as_float(e1.y), acc);
    acc = fmaf(v2, __int_as_float(e2.y), acc);
    acc = fmaf(v3, __int_as_float(e3.y), acc);
  }
  for (; j < e; ++j) {
    int2 ed = sEdge[j];
    acc = fmaf(xp2[ed.x], __int_as_float(ed.y), acc);
  }
  out[i] = acc + b2[0];
}

// ---------------- launch ----------------

extern "C" void kernel_launch(void* const* d_in, const int* in_sizes, int n_in,
                              void* d_out, int out_size, void* d_ws, size_t ws_size,
                              hipStream_t stream) {
  const float* feat = (const float*)d_in[0];
  const int* ei = (const int*)d_in[1];
  const float* ew = (const float*)d_in[2];
  const float* W0 = (const float*)d_in[3];
  const float* b0 = (const float*)d_in[4];
  const float* W1 = (const float*)d_in[5];
  const float* b1 = (const float*)d_in[6];
  const float* W2 = (const float*)d_in[7];
  const float* b2 = (const float*)d_in[8];
  float* out = (float*)d_out;

  const int N_ = in_sizes[0] / NF;
  const int E_ = in_sizes[2];
  const int* row = ei;
  const int* col = ei + E_;

  char* ws = (char*)d_ws;
  size_t off = 0;
  auto alloc = [&](size_t bytes) -> void* {
    void* p = ws + off;
    off = (off + bytes + 255) & ~(size_t)255;
    return p;
  };
  float* bufA  = (float*)alloc((size_t)N_ * NF * 4);
  float* bufB  = (float*)alloc((size_t)N_ * NF * 4);
  float* deg   = (float*)alloc((size_t)N_ * 4);        // becomes dinv in place
  int*   rowptr= (int*)  alloc(((size_t)N_ + 1) * 4);
  int*   cursor= (int*)  alloc((size_t)N_ * 4);
  int*   cnt   = (int*)  alloc((size_t)N_ * 4);
  int*   bsum  = (int*)  alloc(256 * 4);
  int*   bexcl = (int*)  alloc(256 * 4);
  int2*  sEdge = (int2*) alloc((size_t)E_ * 8);
  float* xp2   = (float*)alloc((size_t)N_ * 4);

  const int nThreads = 256;
  const int gN   = (N_ + nThreads - 1) / nThreads;
  const int gE   = (E_ + nThreads - 1) / nThreads;
  const int gWav = (N_ + 3) / 4;               // one wave per node (64-lane kernels)
  const int gAgg = (N_ + 7) / 8;               // 8 nodes per 256-thread block
  const int nScanBlocks = (N_ + 1023) / 1024;  // <= 256 required

  hipMemsetAsync(cnt, 0, (size_t)N_ * 4, stream);
  k_init_deg<<<gN, nThreads, 0, stream>>>(deg, N_);
  k_rownorm<<<gWav, nThreads, 0, stream>>>(feat, bufA, N_);
  k_edge_pass1<<<gE, nThreads, 0, stream>>>(col, ew, deg, cnt, E_);
  k_dinv<<<gN, nThreads, 0, stream>>>(deg, N_);
  k_scan_local<<<nScanBlocks, nThreads, 0, stream>>>(cnt, rowptr, bsum, N_);
  k_scan_sums<<<1, nThreads, 0, stream>>>(bsum, bexcl, rowptr + N_, nScanBlocks);
  k_scan_add<<<gN, nThreads, 0, stream>>>(rowptr, cursor, bexcl, N_);
  k_edge_scatter<<<gE, nThreads, 0, stream>>>(row, col, ew, deg, cursor, sEdge, E_);

  const int gGemm = (N_ + 63) / 64;
  // layer 0
  k_gemm128<<<gGemm, nThreads, 0, stream>>>(bufA, W0, bufB, N_);
  k_agg128<<<gAgg, nThreads, 0, stream>>>(bufB, rowptr, sEdge, deg, b0, bufA, N_, 1);
  // layer 1
  k_gemm128<<<gGemm, nThreads, 0, stream>>>(bufA, W1, bufB, N_);
  k_agg128<<<gAgg, nThreads, 0, stream>>>(bufB, rowptr, sEdge, deg, b1, bufA, N_, 1);
  // layer 2
  k_gemv<<<gWav, nThreads, 0, stream>>>(bufA, W2, xp2, N_);
  k_agg1<<<gN, nThreads, 0, stream>>>(xp2, rowptr, sEdge, deg, b2, out, N_);
}

// Round 5
// 674.576 us; speedup vs baseline: 1.2862x; 1.1176x over previous
//
#include <hip/hip_runtime.h>

#define NF 128
typedef unsigned long long ull;

// ---------------- row sums (for layer-0 normalization folded into GEMM) ----

__global__ __launch_bounds__(256) void k_rowsum(const float* __restrict__ feat,
                                                float* __restrict__ invs, int n) {
  int gid = blockIdx.x * 256 + threadIdx.x;
  int wave = gid >> 6, lane = gid & 63;
  if (wave >= n) return;
  float2 v = ((const float2*)(feat + (size_t)wave * NF))[lane];
  float s = v.x + v.y;
#pragma unroll
  for (int off = 1; off < 64; off <<= 1) s += __shfl_xor(s, off, 64);
  if (lane == 0) invs[wave] = 1.0f / s;
}

// ---------------- degree + count in ONE packed 64-bit atomic ----------------
// low 32: edge count; high 32: weighted degree in 8.24 fixed point.

__global__ __launch_bounds__(256) void k_edge_pass1(const int* __restrict__ col,
                                                    const float* __restrict__ w,
                                                    ull* __restrict__ packed, int ne) {
  int e = blockIdx.x * 256 + threadIdx.x;
  if (e >= ne) return;
  int c = col[e];
  unsigned fix = (unsigned)__float2uint_rn(w[e] * 16777216.0f);  // w * 2^24
  atomicAdd(&packed[c], ((ull)fix << 32) | 1ull);
}

__global__ __launch_bounds__(256) void k_finish(const ull* __restrict__ packed,
                                                float* __restrict__ dinv,
                                                int* __restrict__ cnt, int n) {
  int i = blockIdx.x * 256 + threadIdx.x;
  if (i >= n) return;
  ull p = packed[i];
  float deg = (float)(unsigned)(p >> 32) * (1.0f / 16777216.0f) + 1.0f;  // +self loop
  dinv[i] = rsqrtf(deg);
  cnt[i] = (int)(unsigned)(p & 0xffffffffu);
}

// ---------------- exclusive scan (3-kernel), 1024 items/block ----------------

__global__ __launch_bounds__(256) void k_scan_local(const int* __restrict__ cnt,
                                                    int* __restrict__ excl,
                                                    int* __restrict__ bsum, int n) {
  __shared__ int sd[256];
  int tid = threadIdx.x;
  int idx = blockIdx.x * 1024 + tid * 4;
  int4 v = {0, 0, 0, 0};
  if (idx + 4 <= n) {
    v = *(const int4*)&cnt[idx];
  } else {
    if (idx < n)     v.x = cnt[idx];
    if (idx + 1 < n) v.y = cnt[idx + 1];
    if (idx + 2 < n) v.z = cnt[idx + 2];
    if (idx + 3 < n) v.w = cnt[idx + 3];
  }
  int tsum = v.x + v.y + v.z + v.w;
  sd[tid] = tsum;
  __syncthreads();
  for (int off = 1; off < 256; off <<= 1) {
    int t = (tid >= off) ? sd[tid - off] : 0;
    __syncthreads();
    sd[tid] += t;
    __syncthreads();
  }
  int texcl = sd[tid] - tsum;
  if (tid == 255) bsum[blockIdx.x] = sd[255];
  int4 w;
  w.x = texcl; w.y = texcl + v.x; w.z = texcl + v.x + v.y; w.w = texcl + v.x + v.y + v.z;
  if (idx + 4 <= n) {
    *(int4*)&excl[idx] = w;
  } else {
    if (idx < n)     excl[idx] = w.x;
    if (idx + 1 < n) excl[idx + 1] = w.y;
    if (idx + 2 < n) excl[idx + 2] = w.z;
    if (idx + 3 < n) excl[idx + 3] = w.w;
  }
}

__global__ __launch_bounds__(256) void k_scan_sums(const int* __restrict__ bsum,
                                                   int* __restrict__ bexcl,
                                                   int* __restrict__ rowptr_end, int nb) {
  __shared__ int sd[256];
  int tid = threadIdx.x;
  int v = (tid < nb) ? bsum[tid] : 0;
  sd[tid] = v;
  __syncthreads();
  for (int off = 1; off < 256; off <<= 1) {
    int t = (tid >= off) ? sd[tid - off] : 0;
    __syncthreads();
    sd[tid] += t;
    __syncthreads();
  }
  if (tid < nb) bexcl[tid] = sd[tid] - v;
  if (tid == 255) rowptr_end[0] = sd[255];
}

__global__ __launch_bounds__(256) void k_scan_add(int* __restrict__ rowptr,
                                                  int* __restrict__ cursor,
                                                  const int* __restrict__ bexcl, int n) {
  int i = blockIdx.x * 256 + threadIdx.x;
  if (i >= n) return;
  int v = rowptr[i] + bexcl[i >> 10];
  rowptr[i] = v;
  cursor[i] = v;
}

// ---------------- CSC scatter: packed (row, dinv[r]*w) per edge --------------

__global__ __launch_bounds__(256) void k_edge_scatter(const int* __restrict__ row,
                                                      const int* __restrict__ col,
                                                      const float* __restrict__ w,
                                                      const float* __restrict__ dinv,
                                                      int* __restrict__ cursor,
                                                      int2* __restrict__ sEdge, int ne) {
  int e = blockIdx.x * 256 + threadIdx.x;
  if (e >= ne) return;
  int r = row[e], c = col[e];
  int pos = atomicAdd(&cursor[c], 1);
  float nrm = dinv[r] * w[e];  // dinv[c] applied in the agg kernel
  sEdge[pos] = make_int2(r, __float_as_int(nrm));
}

// ---------------- GEMM: Y[n,128] = diag(scale) X[n,128] @ W[128,128] --------

__global__ __launch_bounds__(256, 2) void k_gemm128(const float* __restrict__ X,
                                                    const float* __restrict__ W,
                                                    float* __restrict__ Y, int n,
                                                    const float* __restrict__ scale) {
  __shared__ float Ws[128 * 128];
  __shared__ float Xs[64 * 36];
  const int tid = threadIdx.x;
  for (int i = tid * 4; i < 128 * 128; i += 256 * 4)
    *(float4*)&Ws[i] = *(const float4*)&W[i];

  int r0 = blockIdx.x * 64;
  int tcol = tid & 15, trow = tid >> 4;
  float acc[4][8] = {};

  for (int kc = 0; kc < 128; kc += 32) {
    __syncthreads();
    {
      int rr = tid >> 2;
      int cc = (tid & 3) * 8;
      int grow = r0 + rr;
      if (grow >= n) grow = n - 1;
      float sc = scale ? scale[grow] : 1.0f;
      const float* src = X + (size_t)grow * NF + kc + cc;
      float4 a = *(const float4*)src;
      float4 b = *(const float4*)(src + 4);
      a.x *= sc; a.y *= sc; a.z *= sc; a.w *= sc;
      b.x *= sc; b.y *= sc; b.z *= sc; b.w *= sc;
      *(float4*)&Xs[rr * 36 + cc] = a;
      *(float4*)&Xs[rr * 36 + cc + 4] = b;
    }
    __syncthreads();
#pragma unroll
    for (int k4 = 0; k4 < 32; k4 += 4) {
      float4 xv[4];
#pragma unroll
      for (int i = 0; i < 4; i++)
        xv[i] = *(const float4*)&Xs[(trow * 4 + i) * 36 + k4];
#pragma unroll
      for (int kk = 0; kk < 4; kk++) {
        float4 w0 = *(const float4*)&Ws[(kc + k4 + kk) * 128 + tcol * 4];
        float4 w1 = *(const float4*)&Ws[(kc + k4 + kk) * 128 + 64 + tcol * 4];
#pragma unroll
        for (int i = 0; i < 4; i++) {
          float xx = ((const float*)&xv[i])[kk];
          acc[i][0] = fmaf(xx, w0.x, acc[i][0]);
          acc[i][1] = fmaf(xx, w0.y, acc[i][1]);
          acc[i][2] = fmaf(xx, w0.z, acc[i][2]);
          acc[i][3] = fmaf(xx, w0.w, acc[i][3]);
          acc[i][4] = fmaf(xx, w1.x, acc[i][4]);
          acc[i][5] = fmaf(xx, w1.y, acc[i][5]);
          acc[i][6] = fmaf(xx, w1.z, acc[i][6]);
          acc[i][7] = fmaf(xx, w1.w, acc[i][7]);
        }
      }
    }
  }
#pragma unroll
  for (int i = 0; i < 4; i++) {
    int gr = r0 + trow * 4 + i;
    if (gr < n) {
      *(float4*)&Y[(size_t)gr * NF + tcol * 4] = *(float4*)&acc[i][0];
      *(float4*)&Y[(size_t)gr * NF + 64 + tcol * 4] = *(float4*)&acc[i][4];
    }
  }
}

// ---------------- pull aggregation, H=128 ----------------
// 2 nodes per wave; x4 unroll -> 8 gathers in flight per wave.
// out = dinv[i] * sum_j(nr_j * x[r_j]) + dinv[i]^2 * x[i] + b

__global__ __launch_bounds__(256) void k_agg128(const float* __restrict__ XP,
                                                const int* __restrict__ rowptr,
                                                const int2* __restrict__ sEdge,
                                                const float* __restrict__ dinv,
                                                const float* __restrict__ bias,
                                                float* __restrict__ Y, int n, int relu) {
  int gid = blockIdx.x * 256 + threadIdx.x;
  int i = gid >> 5;           // node = half-wave id
  int lane = gid & 31;        // float4 slice of the 128-wide row
  if (i >= n) return;
  float di = dinv[i];
  float4 accE = {0.f, 0.f, 0.f, 0.f};
  int s = rowptr[i], e = rowptr[i + 1];
  int j = s;
  for (; j + 4 <= e; j += 4) {
    int2 e0 = sEdge[j], e1 = sEdge[j + 1], e2 = sEdge[j + 2], e3 = sEdge[j + 3];
    const float4* p0 = (const float4*)(XP + (size_t)e0.x * NF);
    const float4* p1 = (const float4*)(XP + (size_t)e1.x * NF);
    const float4* p2 = (const float4*)(XP + (size_t)e2.x * NF);
    const float4* p3 = (const float4*)(XP + (size_t)e3.x * NF);
    float4 v0 = p0[lane], v1 = p1[lane], v2 = p2[lane], v3 = p3[lane];
    float n0 = __int_as_float(e0.y), n1 = __int_as_float(e1.y);
    float n2 = __int_as_float(e2.y), n3 = __int_as_float(e3.y);
    accE.x = fmaf(v0.x, n0, accE.x); accE.y = fmaf(v0.y, n0, accE.y);
    accE.z = fmaf(v0.z, n0, accE.z); accE.w = fmaf(v0.w, n0, accE.w);
    accE.x = fmaf(v1.x, n1, accE.x); accE.y = fmaf(v1.y, n1, accE.y);
    accE.z = fmaf(v1.z, n1, accE.z); accE.w = fmaf(v1.w, n1, accE.w);
    accE.x = fmaf(v2.x, n2, accE.x); accE.y = fmaf(v2.y, n2, accE.y);
    accE.z = fmaf(v2.z, n2, accE.z); accE.w = fmaf(v2.w, n2, accE.w);
    accE.x = fmaf(v3.x, n3, accE.x); accE.y = fmaf(v3.y, n3, accE.y);
    accE.z = fmaf(v3.z, n3, accE.z); accE.w = fmaf(v3.w, n3, accE.w);
  }
  for (; j < e; ++j) {
    int2 ed = sEdge[j];
    float nr = __int_as_float(ed.y);
    float4 v = ((const float4*)(XP + (size_t)ed.x * NF))[lane];
    accE.x = fmaf(v.x, nr, accE.x); accE.y = fmaf(v.y, nr, accE.y);
    accE.z = fmaf(v.z, nr, accE.z); accE.w = fmaf(v.w, nr, accE.w);
  }
  float sn = di * di;
  float4 xv = ((const float4*)(XP + (size_t)i * NF))[lane];
  float4 b = ((const float4*)bias)[lane];
  float4 acc;
  acc.x = fmaf(accE.x, di, fmaf(xv.x, sn, b.x));
  acc.y = fmaf(accE.y, di, fmaf(xv.y, sn, b.y));
  acc.z = fmaf(accE.z, di, fmaf(xv.z, sn, b.z));
  acc.w = fmaf(accE.w, di, fmaf(xv.w, sn, b.w));
  if (relu) {
    acc.x = fmaxf(acc.x, 0.f); acc.y = fmaxf(acc.y, 0.f);
    acc.z = fmaxf(acc.z, 0.f); acc.w = fmaxf(acc.w, 0.f);
  }
  ((float4*)(Y + (size_t)i * NF))[lane] = acc;
}

// ---------------- layer 2: GEMV (H=1) + scalar aggregation ----------------

__global__ __launch_bounds__(256) void k_gemv(const float* __restrict__ X,
                                              const float* __restrict__ w2,
                                              float* __restrict__ y, int n) {
  int gid = blockIdx.x * 256 + threadIdx.x;
  int i = gid >> 6, lane = gid & 63;
  if (i >= n) return;
  float2 x = ((const float2*)(X + (size_t)i * NF))[lane];
  float2 w = ((const float2*)w2)[lane];
  float s = x.x * w.x + x.y * w.y;
#pragma unroll
  for (int off = 1; off < 64; off <<= 1) s += __shfl_xor(s, off, 64);
  if (lane == 0) y[i] = s;
}

__global__ __launch_bounds__(256) void k_agg1(const float* __restrict__ xp2,
                                              const int* __restrict__ rowptr,
                                              const int2* __restrict__ sEdge,
                                              const float* __restrict__ dinv,
                                              const float* __restrict__ b2,
                                              float* __restrict__ out, int n) {
  int i = blockIdx.x * 256 + threadIdx.x;
  if (i >= n) return;
  float di = dinv[i];
  float accE = 0.0f;
  int s = rowptr[i], e = rowptr[i + 1];
  int j = s;
  for (; j + 4 <= e; j += 4) {
    int2 e0 = sEdge[j], e1 = sEdge[j + 1], e2 = sEdge[j + 2], e3 = sEdge[j + 3];
    float v0 = xp2[e0.x], v1 = xp2[e1.x], v2 = xp2[e2.x], v3 = xp2[e3.x];
    accE = fmaf(v0, __int_as_float(e0.y), accE);
    accE = fmaf(v1, __int_as_float(e1.y), accE);
    accE = fmaf(v2, __int_as_float(e2.y), accE);
    accE = fmaf(v3, __int_as_float(e3.y), accE);
  }
  for (; j < e; ++j) {
    int2 ed = sEdge[j];
    accE = fmaf(xp2[ed.x], __int_as_float(ed.y), accE);
  }
  out[i] = fmaf(accE, di, fmaf(xp2[i], di * di, b2[0]));
}

// ---------------- launch ----------------

extern "C" void kernel_launch(void* const* d_in, const int* in_sizes, int n_in,
                              void* d_out, int out_size, void* d_ws, size_t ws_size,
                              hipStream_t stream) {
  const float* feat = (const float*)d_in[0];
  const int* ei = (const int*)d_in[1];
  const float* ew = (const float*)d_in[2];
  const float* W0 = (const float*)d_in[3];
  const float* b0 = (const float*)d_in[4];
  const float* W1 = (const float*)d_in[5];
  const float* b1 = (const float*)d_in[6];
  const float* W2 = (const float*)d_in[7];
  const float* b2 = (const float*)d_in[8];
  float* out = (float*)d_out;

  const int N_ = in_sizes[0] / NF;
  const int E_ = in_sizes[2];
  const int* row = ei;
  const int* col = ei + E_;

  char* ws = (char*)d_ws;
  size_t off = 0;
  auto alloc = [&](size_t bytes) -> void* {
    void* p = ws + off;
    off = (off + bytes + 255) & ~(size_t)255;
    return p;
  };
  float* bufA  = (float*)alloc((size_t)N_ * NF * 4);
  float* bufB  = (float*)alloc((size_t)N_ * NF * 4);
  ull*   packed= (ull*)  alloc((size_t)N_ * 8);        // cursor aliases this later
  float* dinv  = (float*)alloc((size_t)N_ * 4);
  float* invs  = (float*)alloc((size_t)N_ * 4);
  int*   rowptr= (int*)  alloc(((size_t)N_ + 1) * 4);
  int*   cnt   = (int*)  alloc((size_t)N_ * 4);
  int*   bsum  = (int*)  alloc(256 * 4);
  int*   bexcl = (int*)  alloc(256 * 4);
  int2*  sEdge = (int2*) alloc((size_t)E_ * 8);
  float* xp2   = (float*)alloc((size_t)N_ * 4);
  int*   cursor= (int*)packed;  // packed is dead after k_finish

  const int nThreads = 256;
  const int gN   = (N_ + nThreads - 1) / nThreads;
  const int gE   = (E_ + nThreads - 1) / nThreads;
  const int gWav = (N_ + 3) / 4;               // one wave per node (64-lane kernels)
  const int gAgg = (N_ + 7) / 8;               // 8 nodes per 256-thread block
  const int nScanBlocks = (N_ + 1023) / 1024;  // <= 256 required

  hipMemsetAsync(packed, 0, (size_t)N_ * 8, stream);
  k_rowsum<<<gWav, nThreads, 0, stream>>>(feat, invs, N_);
  k_edge_pass1<<<gE, nThreads, 0, stream>>>(col, ew, packed, E_);
  k_finish<<<gN, nThreads, 0, stream>>>(packed, dinv, cnt, N_);
  k_scan_local<<<nScanBlocks, nThreads, 0, stream>>>(cnt, rowptr, bsum, N_);
  k_scan_sums<<<1, nThreads, 0, stream>>>(bsum, bexcl, rowptr + N_, nScanBlocks);
  k_scan_add<<<gN, nThreads, 0, stream>>>(rowptr, cursor, bexcl, N_);
  k_edge_scatter<<<gE, nThreads, 0, stream>>>(row, col, ew, dinv, cursor, sEdge, E_);

  const int gGemm = (N_ + 63) / 64;
  // layer 0 (row-normalization folded into GEMM via invs)
  k_gemm128<<<gGemm, nThreads, 0, stream>>>(feat, W0, bufB, N_, invs);
  k_agg128<<<gAgg, nThreads, 0, stream>>>(bufB, rowptr, sEdge, dinv, b0, bufA, N_, 1);
  // layer 1
  k_gemm128<<<gGemm, nThreads, 0, stream>>>(bufA, W1, bufB, N_, nullptr);
  k_agg128<<<gAgg, nThreads, 0, stream>>>(bufB, rowptr, sEdge, dinv, b1, bufA, N_, 1);
  // layer 2
  k_gemv<<<gWav, nThreads, 0, stream>>>(bufA, W2, xp2, N_);
  k_agg1<<<gN, nThreads, 0, stream>>>(xp2, rowptr, sEdge, dinv, b2, out, N_);
}

// Round 8
// 557.981 us; speedup vs baseline: 1.5550x; 1.2090x over previous
//
#include <hip/hip_runtime.h>

#define NF 128
typedef unsigned long long ull;
typedef unsigned int uint;

// ---------------- bf16 helpers ----------------

__device__ __forceinline__ float bflo(uint u) { return __uint_as_float(u << 16); }
__device__ __forceinline__ float bfhi(uint u) { return __uint_as_float(u & 0xffff0000u); }
__device__ __forceinline__ uint pack_bf16(float a, float b) {  // RNE
  uint ua = __float_as_uint(a), ub = __float_as_uint(b);
  ua = (ua + 0x7fffu + ((ua >> 16) & 1u)) >> 16;
  ub = (ub + 0x7fffu + ((ub >> 16) & 1u)) & 0xffff0000u;
  return ua | ub;
}

// ---------------- row sums (layer-0 normalization folded into GEMM) --------

__global__ __launch_bounds__(256) void k_rowsum(const float* __restrict__ feat,
                                                float* __restrict__ invs, int n) {
  int gid = blockIdx.x * 256 + threadIdx.x;
  int wave = gid >> 6, lane = gid & 63;
  if (wave >= n) return;
  float2 v = ((const float2*)(feat + (size_t)wave * NF))[lane];
  float s = v.x + v.y;
#pragma unroll
  for (int off = 1; off < 64; off <<= 1) s += __shfl_xor(s, off, 64);
  if (lane == 0) invs[wave] = 1.0f / s;
}

// ---------------- degree + count in ONE packed 64-bit atomic ----------------

__global__ __launch_bounds__(256) void k_edge_pass1(const int* __restrict__ col,
                                                    const float* __restrict__ w,
                                                    ull* __restrict__ packed, int ne) {
  int e = blockIdx.x * 256 + threadIdx.x;
  if (e >= ne) return;
  int c = col[e];
  unsigned fix = (unsigned)__float2uint_rn(w[e] * 16777216.0f);  // w * 2^24
  atomicAdd(&packed[c], ((ull)fix << 32) | 1ull);
}

__global__ __launch_bounds__(256) void k_finish(const ull* __restrict__ packed,
                                                float* __restrict__ dinv,
                                                int* __restrict__ cnt, int n) {
  int i = blockIdx.x * 256 + threadIdx.x;
  if (i >= n) return;
  ull p = packed[i];
  float deg = (float)(unsigned)(p >> 32) * (1.0f / 16777216.0f) + 1.0f;  // +self loop
  dinv[i] = rsqrtf(deg);
  cnt[i] = (int)(unsigned)(p & 0xffffffffu);
}

// ---------------- exclusive scan (3-kernel), 1024 items/block ----------------

__global__ __launch_bounds__(256) void k_scan_local(const int* __restrict__ cnt,
                                                    int* __restrict__ excl,
                                                    int* __restrict__ bsum, int n) {
  __shared__ int sd[256];
  int tid = threadIdx.x;
  int idx = blockIdx.x * 1024 + tid * 4;
  int4 v = {0, 0, 0, 0};
  if (idx + 4 <= n) {
    v = *(const int4*)&cnt[idx];
  } else {
    if (idx < n)     v.x = cnt[idx];
    if (idx + 1 < n) v.y = cnt[idx + 1];
    if (idx + 2 < n) v.z = cnt[idx + 2];
    if (idx + 3 < n) v.w = cnt[idx + 3];
  }
  int tsum = v.x + v.y + v.z + v.w;
  sd[tid] = tsum;
  __syncthreads();
  for (int off = 1; off < 256; off <<= 1) {
    int t = (tid >= off) ? sd[tid - off] : 0;
    __syncthreads();
    sd[tid] += t;
    __syncthreads();
  }
  int texcl = sd[tid] - tsum;
  if (tid == 255) bsum[blockIdx.x] = sd[255];
  int4 w;
  w.x = texcl; w.y = texcl + v.x; w.z = texcl + v.x + v.y; w.w = texcl + v.x + v.y + v.z;
  if (idx + 4 <= n) {
    *(int4*)&excl[idx] = w;
  } else {
    if (idx < n)     excl[idx] = w.x;
    if (idx + 1 < n) excl[idx + 1] = w.y;
    if (idx + 2 < n) excl[idx + 2] = w.z;
    if (idx + 3 < n) excl[idx + 3] = w.w;
  }
}

__global__ __launch_bounds__(256) void k_scan_sums(const int* __restrict__ bsum,
                                                   int* __restrict__ bexcl,
                                                   int* __restrict__ rowptr_end, int nb) {
  __shared__ int sd[256];
  int tid = threadIdx.x;
  int v = (tid < nb) ? bsum[tid] : 0;
  sd[tid] = v;
  __syncthreads();
  for (int off = 1; off < 256; off <<= 1) {
    int t = (tid >= off) ? sd[tid - off] : 0;
    __syncthreads();
    sd[tid] += t;
    __syncthreads();
  }
  if (tid < nb) bexcl[tid] = sd[tid] - v;
  if (tid == 255) rowptr_end[0] = sd[255];
}

__global__ __launch_bounds__(256) void k_scan_add(int* __restrict__ rowptr,
                                                  int* __restrict__ cursor,
                                                  const int* __restrict__ bexcl, int n) {
  int i = blockIdx.x * 256 + threadIdx.x;
  if (i >= n) return;
  int v = rowptr[i] + bexcl[i >> 10];
  rowptr[i] = v;
  cursor[i] = v;
}

// ---------------- CSC scatter: packed (row, dinv[r]*w) per edge --------------

__global__ __launch_bounds__(256) void k_edge_scatter(const int* __restrict__ row,
                                                      const int* __restrict__ col,
                                                      const float* __restrict__ w,
                                                      const float* __restrict__ dinv,
                                                      int* __restrict__ cursor,
                                                      int2* __restrict__ sEdge, int ne) {
  int e = blockIdx.x * 256 + threadIdx.x;
  if (e >= ne) return;
  int r = row[e], c = col[e];
  int pos = atomicAdd(&cursor[c], 1);
  float nrm = dinv[r] * w[e];  // dinv[c] applied in the agg kernel
  sEdge[pos] = make_int2(r, __float_as_int(nrm));
}

// ------- GEMM: Yb[n,128](bf16) = diag(scale) X[n,128] @ W[128,128] ----------

__global__ __launch_bounds__(256, 2) void k_gemm128(const float* __restrict__ X,
                                                    const float* __restrict__ W,
                                                    uint* __restrict__ Yb, int n,
                                                    const float* __restrict__ scale) {
  __shared__ float Ws[128 * 128];
  __shared__ float Xs[64 * 36];
  const int tid = threadIdx.x;
  for (int i = tid * 4; i < 128 * 128; i += 256 * 4)
    *(float4*)&Ws[i] = *(const float4*)&W[i];

  int r0 = blockIdx.x * 64;
  int tcol = tid & 15, trow = tid >> 4;
  float acc[4][8] = {};

  for (int kc = 0; kc < 128; kc += 32) {
    __syncthreads();
    {
      int rr = tid >> 2;
      int cc = (tid & 3) * 8;
      int grow = r0 + rr;
      if (grow >= n) grow = n - 1;
      float sc = scale ? scale[grow] : 1.0f;
      const float* src = X + (size_t)grow * NF + kc + cc;
      float4 a = *(const float4*)src;
      float4 b = *(const float4*)(src + 4);
      a.x *= sc; a.y *= sc; a.z *= sc; a.w *= sc;
      b.x *= sc; b.y *= sc; b.z *= sc; b.w *= sc;
      *(float4*)&Xs[rr * 36 + cc] = a;
      *(float4*)&Xs[rr * 36 + cc + 4] = b;
    }
    __syncthreads();
#pragma unroll
    for (int k4 = 0; k4 < 32; k4 += 4) {
      float4 xv[4];
#pragma unroll
      for (int i = 0; i < 4; i++)
        xv[i] = *(const float4*)&Xs[(trow * 4 + i) * 36 + k4];
#pragma unroll
      for (int kk = 0; kk < 4; kk++) {
        float4 w0 = *(const float4*)&Ws[(kc + k4 + kk) * 128 + tcol * 4];
        float4 w1 = *(const float4*)&Ws[(kc + k4 + kk) * 128 + 64 + tcol * 4];
#pragma unroll
        for (int i = 0; i < 4; i++) {
          float xx = ((const float*)&xv[i])[kk];
          acc[i][0] = fmaf(xx, w0.x, acc[i][0]);
          acc[i][1] = fmaf(xx, w0.y, acc[i][1]);
          acc[i][2] = fmaf(xx, w0.z, acc[i][2]);
          acc[i][3] = fmaf(xx, w0.w, acc[i][3]);
          acc[i][4] = fmaf(xx, w1.x, acc[i][4]);
          acc[i][5] = fmaf(xx, w1.y, acc[i][5]);
          acc[i][6] = fmaf(xx, w1.z, acc[i][6]);
          acc[i][7] = fmaf(xx, w1.w, acc[i][7]);
        }
      }
    }
  }
#pragma unroll
  for (int i = 0; i < 4; i++) {
    int gr = r0 + trow * 4 + i;
    if (gr < n) {
      uint2 p0 = {pack_bf16(acc[i][0], acc[i][1]), pack_bf16(acc[i][2], acc[i][3])};
      uint2 p1 = {pack_bf16(acc[i][4], acc[i][5]), pack_bf16(acc[i][6], acc[i][7])};
      *(uint2*)&Yb[(size_t)gr * 64 + tcol * 2] = p0;
      *(uint2*)&Yb[(size_t)gr * 64 + 32 + tcol * 2] = p1;
    }
  }
}

// ---------------- pull aggregation, H=128, bf16 gathers ----------------
// 2 nodes per wave (half-wave = 32 lanes x 8B = 256B bf16 row); 8-edge chunks
// -> 16 gathers in flight per wave. fp32 accumulate, fp32 output.
// out = dinv[i] * sum_j(nr_j * xb[r_j]) + dinv[i]^2 * xb[i] + b

__global__ __launch_bounds__(256) void k_agg128b(const uint* __restrict__ XPb,
                                                 const int* __restrict__ rowptr,
                                                 const int2* __restrict__ sEdge,
                                                 const float* __restrict__ dinv,
                                                 const float* __restrict__ bias,
                                                 float* __restrict__ Y, int n, int relu) {
  int gid = blockIdx.x * 256 + threadIdx.x;
  int i = gid >> 5;           // node = half-wave id
  int lane = gid & 31;        // 4-elem (8B) slice of the 128-wide bf16 row
  if (i >= n) return;
  float di = dinv[i];
  uint2 xv = ((const uint2*)XPb)[(size_t)i * 32 + lane];   // self row (in flight early)
  float4 b4 = ((const float4*)bias)[lane];
  int s = rowptr[i], e = rowptr[i + 1];
  float4 acc = {0.f, 0.f, 0.f, 0.f};
  int j = s;

#define GATHER(d, g) \
  uint2 g = ((const uint2*)XPb)[(size_t)(d).x * 32 + lane];
#define ACCUM(d, g) { \
  float nr = __int_as_float((d).y); \
  acc.x = fmaf(bflo(g.x), nr, acc.x); acc.y = fmaf(bfhi(g.x), nr, acc.y); \
  acc.z = fmaf(bflo(g.y), nr, acc.z); acc.w = fmaf(bfhi(g.y), nr, acc.w); }

  for (; j + 8 <= e; j += 8) {
    int2 d0 = sEdge[j],     d1 = sEdge[j + 1], d2 = sEdge[j + 2], d3 = sEdge[j + 3];
    int2 d4 = sEdge[j + 4], d5 = sEdge[j + 5], d6 = sEdge[j + 6], d7 = sEdge[j + 7];
    GATHER(d0, g0) GATHER(d1, g1) GATHER(d2, g2) GATHER(d3, g3)
    GATHER(d4, g4) GATHER(d5, g5) GATHER(d6, g6) GATHER(d7, g7)
    ACCUM(d0, g0) ACCUM(d1, g1) ACCUM(d2, g2) ACCUM(d3, g3)
    ACCUM(d4, g4) ACCUM(d5, g5) ACCUM(d6, g6) ACCUM(d7, g7)
  }
  if (j + 4 <= e) {
    int2 d0 = sEdge[j], d1 = sEdge[j + 1], d2 = sEdge[j + 2], d3 = sEdge[j + 3];
    GATHER(d0, g0) GATHER(d1, g1) GATHER(d2, g2) GATHER(d3, g3)
    ACCUM(d0, g0) ACCUM(d1, g1) ACCUM(d2, g2) ACCUM(d3, g3)
    j += 4;
  }
  for (; j < e; ++j) {
    int2 d0 = sEdge[j];
    GATHER(d0, g0)
    ACCUM(d0, g0)
  }
#undef GATHER
#undef ACCUM

  float sn = di * di;
  float4 acco;
  acco.x = fmaf(acc.x, di, fmaf(bflo(xv.x), sn, b4.x));
  acco.y = fmaf(acc.y, di, fmaf(bfhi(xv.x), sn, b4.y));
  acco.z = fmaf(acc.z, di, fmaf(bflo(xv.y), sn, b4.z));
  acco.w = fmaf(acc.w, di, fmaf(bfhi(xv.y), sn, b4.w));
  if (relu) {
    acco.x = fmaxf(acco.x, 0.f); acco.y = fmaxf(acco.y, 0.f);
    acco.z = fmaxf(acco.z, 0.f); acco.w = fmaxf(acco.w, 0.f);
  }
  ((float4*)(Y + (size_t)i * NF))[lane] = acco;
}

// ---------------- layer 2: GEMV (H=1) + scalar aggregation ----------------

__global__ __launch_bounds__(256) void k_gemv(const float* __restrict__ X,
                                              const float* __restrict__ w2,
                                              float* __restrict__ y, int n) {
  int gid = blockIdx.x * 256 + threadIdx.x;
  int i = gid >> 6, lane = gid & 63;
  if (i >= n) return;
  float2 x = ((const float2*)(X + (size_t)i * NF))[lane];
  float2 w = ((const float2*)w2)[lane];
  float s = x.x * w.x + x.y * w.y;
#pragma unroll
  for (int off = 1; off < 64; off <<= 1) s += __shfl_xor(s, off, 64);
  if (lane == 0) y[i] = s;
}

__global__ __launch_bounds__(256) void k_agg1(const float* __restrict__ xp2,
                                              const int* __restrict__ rowptr,
                                              const int2* __restrict__ sEdge,
                                              const float* __restrict__ dinv,
                                              const float* __restrict__ b2,
                                              float* __restrict__ out, int n) {
  int i = blockIdx.x * 256 + threadIdx.x;
  if (i >= n) return;
  float di = dinv[i];
  float accE = 0.0f;
  int s = rowptr[i], e = rowptr[i + 1];
  int j = s;
  for (; j + 4 <= e; j += 4) {
    int2 e0 = sEdge[j], e1 = sEdge[j + 1], e2 = sEdge[j + 2], e3 = sEdge[j + 3];
    float v0 = xp2[e0.x], v1 = xp2[e1.x], v2 = xp2[e2.x], v3 = xp2[e3.x];
    accE = fmaf(v0, __int_as_float(e0.y), accE);
    accE = fmaf(v1, __int_as_float(e1.y), accE);
    accE = fmaf(v2, __int_as_float(e2.y), accE);
    accE = fmaf(v3, __int_as_float(e3.y), accE);
  }
  for (; j < e; ++j) {
    int2 ed = sEdge[j];
    accE = fmaf(xp2[ed.x], __int_as_float(ed.y), accE);
  }
  out[i] = fmaf(accE, di, fmaf(xp2[i], di * di, b2[0]));
}

// ---------------- launch ----------------

extern "C" void kernel_launch(void* const* d_in, const int* in_sizes, int n_in,
                              void* d_out, int out_size, void* d_ws, size_t ws_size,
                              hipStream_t stream) {
  const float* feat = (const float*)d_in[0];
  const int* ei = (const int*)d_in[1];
  const float* ew = (const float*)d_in[2];
  const float* W0 = (const float*)d_in[3];
  const float* b0 = (const float*)d_in[4];
  const float* W1 = (const float*)d_in[5];
  const float* b1 = (const float*)d_in[6];
  const float* W2 = (const float*)d_in[7];
  const float* b2 = (const float*)d_in[8];
  float* out = (float*)d_out;

  const int N_ = in_sizes[0] / NF;
  const int E_ = in_sizes[2];
  const int* row = ei;
  const int* col = ei + E_;

  char* ws = (char*)d_ws;
  size_t off = 0;
  auto alloc = [&](size_t bytes) -> void* {
    void* p = ws + off;
    off = (off + bytes + 255) & ~(size_t)255;
    return p;
  };
  float* bufA  = (float*)alloc((size_t)N_ * NF * 4);   // fp32 agg outputs
  uint*  bufBb = (uint*) alloc((size_t)N_ * NF * 2);   // bf16 GEMM outputs (XP)
  ull*   packed= (ull*)  alloc((size_t)N_ * 8);        // cursor aliases this later
  float* dinv  = (float*)alloc((size_t)N_ * 4);
  float* invs  = (float*)alloc((size_t)N_ * 4);
  int*   rowptr= (int*)  alloc(((size_t)N_ + 1) * 4);
  int*   cnt   = (int*)  alloc((size_t)N_ * 4);
  int*   bsum  = (int*)  alloc(256 * 4);
  int*   bexcl = (int*)  alloc(256 * 4);
  int2*  sEdge = (int2*) alloc((size_t)E_ * 8);
  float* xp2   = (float*)alloc((size_t)N_ * 4);
  int*   cursor= (int*)packed;  // packed is dead after k_finish

  const int nThreads = 256;
  const int gN   = (N_ + nThreads - 1) / nThreads;
  const int gE   = (E_ + nThreads - 1) / nThreads;
  const int gWav = (N_ + 3) / 4;               // one wave per node (64-lane kernels)
  const int gAgg = (N_ + 7) / 8;               // 8 nodes per 256-thread block
  const int nScanBlocks = (N_ + 1023) / 1024;  // <= 256 required

  hipMemsetAsync(packed, 0, (size_t)N_ * 8, stream);
  k_rowsum<<<gWav, nThreads, 0, stream>>>(feat, invs, N_);
  k_edge_pass1<<<gE, nThreads, 0, stream>>>(col, ew, packed, E_);
  k_finish<<<gN, nThreads, 0, stream>>>(packed, dinv, cnt, N_);
  k_scan_local<<<nScanBlocks, nThreads, 0, stream>>>(cnt, rowptr, bsum, N_);
  k_scan_sums<<<1, nThreads, 0, stream>>>(bsum, bexcl, rowptr + N_, nScanBlocks);
  k_scan_add<<<gN, nThreads, 0, stream>>>(rowptr, cursor, bexcl, N_);
  k_edge_scatter<<<gE, nThreads, 0, stream>>>(row, col, ew, dinv, cursor, sEdge, E_);

  const int gGemm = (N_ + 63) / 64;
  // layer 0 (row-normalization folded into GEMM via invs; bf16 XP out)
  k_gemm128<<<gGemm, nThreads, 0, stream>>>(feat, W0, bufBb, N_, invs);
  k_agg128b<<<gAgg, nThreads, 0, stream>>>(bufBb, rowptr, sEdge, dinv, b0, bufA, N_, 1);
  // layer 1
  k_gemm128<<<gGemm, nThreads, 0, stream>>>(bufA, W1, bufBb, N_, nullptr);
  k_agg128b<<<gAgg, nThreads, 0, stream>>>(bufBb, rowptr, sEdge, dinv, b1, bufA, N_, 1);
  // layer 2
  k_gemv<<<gWav, nThreads, 0, stream>>>(bufA, W2, xp2, N_);
  k_agg1<<<gN, nThreads, 0, stream>>>(xp2, rowptr, sEdge, dinv, b2, out, N_);
}

// Round 9
// 555.597 us; speedup vs baseline: 1.5616x; 1.0043x over previous
//
#include <hip/hip_runtime.h>

#define NF 128
typedef unsigned long long ull;
typedef unsigned int uint;

// ---------------- bf16 helpers ----------------

__device__ __forceinline__ float bflo(uint u) { return __uint_as_float(u << 16); }
__device__ __forceinline__ float bfhi(uint u) { return __uint_as_float(u & 0xffff0000u); }
__device__ __forceinline__ uint pack_bf16(float a, float b) {  // RNE
  uint ua = __float_as_uint(a), ub = __float_as_uint(b);
  ua = (ua + 0x7fffu + ((ua >> 16) & 1u)) >> 16;
  ub = (ub + 0x7fffu + ((ub >> 16) & 1u)) & 0xffff0000u;
  return ua | ub;
}

// packed CSC edge entry: [31:17] = norm q15 fixed point, [16:0] = source row
__device__ __forceinline__ uint pack_edge(uint row, float nrm) {
  uint q = __float2uint_rn(nrm * 32768.0f);
  q = q > 32767u ? 32767u : q;
  return (q << 17) | row;
}

// ---------------- row sums (layer-0 normalization folded into GEMM) --------

__global__ __launch_bounds__(256) void k_rowsum(const float* __restrict__ feat,
                                                float* __restrict__ invs, int n) {
  int gid = blockIdx.x * 256 + threadIdx.x;
  int wave = gid >> 6, lane = gid & 63;
  if (wave >= n) return;
  float2 v = ((const float2*)(feat + (size_t)wave * NF))[lane];
  float s = v.x + v.y;
#pragma unroll
  for (int off = 1; off < 64; off <<= 1) s += __shfl_xor(s, off, 64);
  if (lane == 0) invs[wave] = 1.0f / s;
}

// ---------------- degree + count in ONE packed 64-bit atomic ----------------

__global__ __launch_bounds__(256) void k_edge_pass1(const int* __restrict__ col,
                                                    const float* __restrict__ w,
                                                    ull* __restrict__ packed, int ne) {
  int e = blockIdx.x * 256 + threadIdx.x;
  if (e >= ne) return;
  int c = col[e];
  unsigned fix = (unsigned)__float2uint_rn(w[e] * 16777216.0f);  // w * 2^24
  atomicAdd(&packed[c], ((ull)fix << 32) | 1ull);
}

__global__ __launch_bounds__(256) void k_finish(const ull* __restrict__ packed,
                                                float* __restrict__ dinv,
                                                int* __restrict__ cnt, int n) {
  int i = blockIdx.x * 256 + threadIdx.x;
  if (i >= n) return;
  ull p = packed[i];
  float deg = (float)(unsigned)(p >> 32) * (1.0f / 16777216.0f) + 1.0f;  // +self loop
  dinv[i] = rsqrtf(deg);
  cnt[i] = (int)(unsigned)(p & 0xffffffffu);
}

// ---------------- exclusive scan (3-kernel), 1024 items/block ----------------

__global__ __launch_bounds__(256) void k_scan_local(const int* __restrict__ cnt,
                                                    int* __restrict__ excl,
                                                    int* __restrict__ bsum, int n) {
  __shared__ int sd[256];
  int tid = threadIdx.x;
  int idx = blockIdx.x * 1024 + tid * 4;
  int4 v = {0, 0, 0, 0};
  if (idx + 4 <= n) {
    v = *(const int4*)&cnt[idx];
  } else {
    if (idx < n)     v.x = cnt[idx];
    if (idx + 1 < n) v.y = cnt[idx + 1];
    if (idx + 2 < n) v.z = cnt[idx + 2];
    if (idx + 3 < n) v.w = cnt[idx + 3];
  }
  int tsum = v.x + v.y + v.z + v.w;
  sd[tid] = tsum;
  __syncthreads();
  for (int off = 1; off < 256; off <<= 1) {
    int t = (tid >= off) ? sd[tid - off] : 0;
    __syncthreads();
    sd[tid] += t;
    __syncthreads();
  }
  int texcl = sd[tid] - tsum;
  if (tid == 255) bsum[blockIdx.x] = sd[255];
  int4 w;
  w.x = texcl; w.y = texcl + v.x; w.z = texcl + v.x + v.y; w.w = texcl + v.x + v.y + v.z;
  if (idx + 4 <= n) {
    *(int4*)&excl[idx] = w;
  } else {
    if (idx < n)     excl[idx] = w.x;
    if (idx + 1 < n) excl[idx + 1] = w.y;
    if (idx + 2 < n) excl[idx + 2] = w.z;
    if (idx + 3 < n) excl[idx + 3] = w.w;
  }
}

__global__ __launch_bounds__(256) void k_scan_sums(const int* __restrict__ bsum,
                                                   int* __restrict__ bexcl,
                                                   int* __restrict__ rowptr_end, int nb) {
  __shared__ int sd[256];
  int tid = threadIdx.x;
  int v = (tid < nb) ? bsum[tid] : 0;
  sd[tid] = v;
  __syncthreads();
  for (int off = 1; off < 256; off <<= 1) {
    int t = (tid >= off) ? sd[tid - off] : 0;
    __syncthreads();
    sd[tid] += t;
    __syncthreads();
  }
  if (tid < nb) bexcl[tid] = sd[tid] - v;
  if (tid == 255) rowptr_end[0] = sd[255];
}

__global__ __launch_bounds__(256) void k_scan_add(int* __restrict__ rowptr,
                                                  int* __restrict__ cursor,
                                                  const int* __restrict__ bexcl, int n) {
  int i = blockIdx.x * 256 + threadIdx.x;
  if (i >= n) return;
  int v = rowptr[i] + bexcl[i >> 10];
  rowptr[i] = v;
  cursor[i] = v;
}

// ------- CSC scatter: ONE packed u32 (norm q15 | row17) per edge ------------

__global__ __launch_bounds__(256) void k_edge_scatter(const int* __restrict__ row,
                                                      const int* __restrict__ col,
                                                      const float* __restrict__ w,
                                                      const float* __restrict__ dinv,
                                                      int* __restrict__ cursor,
                                                      uint* __restrict__ sEdge, int ne) {
  int e = blockIdx.x * 256 + threadIdx.x;
  if (e >= ne) return;
  int r = row[e], c = col[e];
  int pos = atomicAdd(&cursor[c], 1);
  float nrm = dinv[r] * w[e];  // dinv[c] applied in the agg kernel; nrm < 1.0
  sEdge[pos] = pack_edge((uint)r, nrm);
}

// ------- GEMM: Yb[n,128](bf16) = diag(scale) X[n,128] @ W[128,128] ----------

__global__ __launch_bounds__(256, 2) void k_gemm128(const float* __restrict__ X,
                                                    const float* __restrict__ W,
                                                    uint* __restrict__ Yb, int n,
                                                    const float* __restrict__ scale) {
  __shared__ float Ws[128 * 128];
  __shared__ float Xs[64 * 36];
  const int tid = threadIdx.x;
  for (int i = tid * 4; i < 128 * 128; i += 256 * 4)
    *(float4*)&Ws[i] = *(const float4*)&W[i];

  int r0 = blockIdx.x * 64;
  int tcol = tid & 15, trow = tid >> 4;
  float acc[4][8] = {};

  for (int kc = 0; kc < 128; kc += 32) {
    __syncthreads();
    {
      int rr = tid >> 2;
      int cc = (tid & 3) * 8;
      int grow = r0 + rr;
      if (grow >= n) grow = n - 1;
      float sc = scale ? scale[grow] : 1.0f;
      const float* src = X + (size_t)grow * NF + kc + cc;
      float4 a = *(const float4*)src;
      float4 b = *(const float4*)(src + 4);
      a.x *= sc; a.y *= sc; a.z *= sc; a.w *= sc;
      b.x *= sc; b.y *= sc; b.z *= sc; b.w *= sc;
      *(float4*)&Xs[rr * 36 + cc] = a;
      *(float4*)&Xs[rr * 36 + cc + 4] = b;
    }
    __syncthreads();
#pragma unroll
    for (int k4 = 0; k4 < 32; k4 += 4) {
      float4 xv[4];
#pragma unroll
      for (int i = 0; i < 4; i++)
        xv[i] = *(const float4*)&Xs[(trow * 4 + i) * 36 + k4];
#pragma unroll
      for (int kk = 0; kk < 4; kk++) {
        float4 w0 = *(const float4*)&Ws[(kc + k4 + kk) * 128 + tcol * 4];
        float4 w1 = *(const float4*)&Ws[(kc + k4 + kk) * 128 + 64 + tcol * 4];
#pragma unroll
        for (int i = 0; i < 4; i++) {
          float xx = ((const float*)&xv[i])[kk];
          acc[i][0] = fmaf(xx, w0.x, acc[i][0]);
          acc[i][1] = fmaf(xx, w0.y, acc[i][1]);
          acc[i][2] = fmaf(xx, w0.z, acc[i][2]);
          acc[i][3] = fmaf(xx, w0.w, acc[i][3]);
          acc[i][4] = fmaf(xx, w1.x, acc[i][4]);
          acc[i][5] = fmaf(xx, w1.y, acc[i][5]);
          acc[i][6] = fmaf(xx, w1.z, acc[i][6]);
          acc[i][7] = fmaf(xx, w1.w, acc[i][7]);
        }
      }
    }
  }
#pragma unroll
  for (int i = 0; i < 4; i++) {
    int gr = r0 + trow * 4 + i;
    if (gr < n) {
      uint2 p0 = {pack_bf16(acc[i][0], acc[i][1]), pack_bf16(acc[i][2], acc[i][3])};
      uint2 p1 = {pack_bf16(acc[i][4], acc[i][5]), pack_bf16(acc[i][6], acc[i][7])};
      *(uint2*)&Yb[(size_t)gr * 64 + tcol * 2] = p0;
      *(uint2*)&Yb[(size_t)gr * 64 + 32 + tcol * 2] = p1;
    }
  }
}

// ---------------- pull aggregation, H=128, bf16 gathers ----------------
// 4 nodes per wave (quarter-wave = 16 lanes x uint4 = 256B bf16 row); 8-edge
// chunks -> 32 gathers in flight per wave. fp32 accumulate, fp32 output.
// out = dinv[i] * sum_j(nr_j * xb[r_j]) + dinv[i]^2 * xb[i] + b

__global__ __launch_bounds__(256) void k_agg128b(const uint* __restrict__ XPb,
                                                 const int* __restrict__ rowptr,
                                                 const uint* __restrict__ sEdge,
                                                 const float* __restrict__ dinv,
                                                 const float* __restrict__ bias,
                                                 float* __restrict__ Y, int n, int relu) {
  int gid = blockIdx.x * 256 + threadIdx.x;
  int i = gid >> 4;           // node = quarter-wave id
  int lane = gid & 15;        // 8-elem (16B) slice of the 128-wide bf16 row
  if (i >= n) return;
  float di = dinv[i];
  uint4 xv = ((const uint4*)XPb)[(size_t)i * 16 + lane];   // self row, in flight early
  int s = rowptr[i], e = rowptr[i + 1];
  float acc[8] = {0.f, 0.f, 0.f, 0.f, 0.f, 0.f, 0.f, 0.f};
  int j = s;

#define GATHER(en, g) \
  uint4 g = ((const uint4*)XPb)[(size_t)((en) & 0x1FFFFu) * 16 + lane];
#define ACCUM(en, g) { \
  float nr = (float)((en) >> 17) * (1.0f / 32768.0f); \
  acc[0] = fmaf(bflo(g.x), nr, acc[0]); acc[1] = fmaf(bfhi(g.x), nr, acc[1]); \
  acc[2] = fmaf(bflo(g.y), nr, acc[2]); acc[3] = fmaf(bfhi(g.y), nr, acc[3]); \
  acc[4] = fmaf(bflo(g.z), nr, acc[4]); acc[5] = fmaf(bfhi(g.z), nr, acc[5]); \
  acc[6] = fmaf(bflo(g.w), nr, acc[6]); acc[7] = fmaf(bfhi(g.w), nr, acc[7]); }

  for (; j + 8 <= e; j += 8) {
    uint e0 = sEdge[j],     e1 = sEdge[j + 1], e2 = sEdge[j + 2], e3 = sEdge[j + 3];
    uint e4 = sEdge[j + 4], e5 = sEdge[j + 5], e6 = sEdge[j + 6], e7 = sEdge[j + 7];
    GATHER(e0, g0) GATHER(e1, g1) GATHER(e2, g2) GATHER(e3, g3)
    GATHER(e4, g4) GATHER(e5, g5) GATHER(e6, g6) GATHER(e7, g7)
    ACCUM(e0, g0) ACCUM(e1, g1) ACCUM(e2, g2) ACCUM(e3, g3)
    ACCUM(e4, g4) ACCUM(e5, g5) ACCUM(e6, g6) ACCUM(e7, g7)
  }
  if (j + 4 <= e) {
    uint e0 = sEdge[j], e1 = sEdge[j + 1], e2 = sEdge[j + 2], e3 = sEdge[j + 3];
    GATHER(e0, g0) GATHER(e1, g1) GATHER(e2, g2) GATHER(e3, g3)
    ACCUM(e0, g0) ACCUM(e1, g1) ACCUM(e2, g2) ACCUM(e3, g3)
    j += 4;
  }
  for (; j < e; ++j) {
    uint e0 = sEdge[j];
    GATHER(e0, g0)
    ACCUM(e0, g0)
  }
#undef GATHER
#undef ACCUM

  float sn = di * di;
  float2 b2v;
  float4 o0, o1;
  float4 bA = ((const float4*)bias)[lane * 2];
  float4 bB = ((const float4*)bias)[lane * 2 + 1];
  o0.x = fmaf(acc[0], di, fmaf(bflo(xv.x), sn, bA.x));
  o0.y = fmaf(acc[1], di, fmaf(bfhi(xv.x), sn, bA.y));
  o0.z = fmaf(acc[2], di, fmaf(bflo(xv.y), sn, bA.z));
  o0.w = fmaf(acc[3], di, fmaf(bfhi(xv.y), sn, bA.w));
  o1.x = fmaf(acc[4], di, fmaf(bflo(xv.z), sn, bB.x));
  o1.y = fmaf(acc[5], di, fmaf(bfhi(xv.z), sn, bB.y));
  o1.z = fmaf(acc[6], di, fmaf(bflo(xv.w), sn, bB.z));
  o1.w = fmaf(acc[7], di, fmaf(bfhi(xv.w), sn, bB.w));
  if (relu) {
    o0.x = fmaxf(o0.x, 0.f); o0.y = fmaxf(o0.y, 0.f);
    o0.z = fmaxf(o0.z, 0.f); o0.w = fmaxf(o0.w, 0.f);
    o1.x = fmaxf(o1.x, 0.f); o1.y = fmaxf(o1.y, 0.f);
    o1.z = fmaxf(o1.z, 0.f); o1.w = fmaxf(o1.w, 0.f);
  }
  ((float4*)(Y + (size_t)i * NF))[lane * 2] = o0;
  ((float4*)(Y + (size_t)i * NF))[lane * 2 + 1] = o1;
}

// ---------------- layer 2: GEMV (H=1) + scalar aggregation ----------------

__global__ __launch_bounds__(256) void k_gemv(const float* __restrict__ X,
                                              const float* __restrict__ w2,
                                              float* __restrict__ y, int n) {
  int gid = blockIdx.x * 256 + threadIdx.x;
  int i = gid >> 6, lane = gid & 63;
  if (i >= n) return;
  float2 x = ((const float2*)(X + (size_t)i * NF))[lane];
  float2 w = ((const float2*)w2)[lane];
  float s = x.x * w.x + x.y * w.y;
#pragma unroll
  for (int off = 1; off < 64; off <<= 1) s += __shfl_xor(s, off, 64);
  if (lane == 0) y[i] = s;
}

__global__ __launch_bounds__(256) void k_agg1(const float* __restrict__ xp2,
                                              const int* __restrict__ rowptr,
                                              const uint* __restrict__ sEdge,
                                              const float* __restrict__ dinv,
                                              const float* __restrict__ b2,
                                              float* __restrict__ out, int n) {
  int i = blockIdx.x * 256 + threadIdx.x;
  if (i >= n) return;
  float di = dinv[i];
  float accE = 0.0f;
  int s = rowptr[i], e = rowptr[i + 1];
  int j = s;
  for (; j + 4 <= e; j += 4) {
    uint e0 = sEdge[j], e1 = sEdge[j + 1], e2 = sEdge[j + 2], e3 = sEdge[j + 3];
    float v0 = xp2[e0 & 0x1FFFFu], v1 = xp2[e1 & 0x1FFFFu];
    float v2 = xp2[e2 & 0x1FFFFu], v3 = xp2[e3 & 0x1FFFFu];
    accE = fmaf(v0, (float)(e0 >> 17) * (1.0f / 32768.0f), accE);
    accE = fmaf(v1, (float)(e1 >> 17) * (1.0f / 32768.0f), accE);
    accE = fmaf(v2, (float)(e2 >> 17) * (1.0f / 32768.0f), accE);
    accE = fmaf(v3, (float)(e3 >> 17) * (1.0f / 32768.0f), accE);
  }
  for (; j < e; ++j) {
    uint e0 = sEdge[j];
    accE = fmaf(xp2[e0 & 0x1FFFFu], (float)(e0 >> 17) * (1.0f / 32768.0f), accE);
  }
  out[i] = fmaf(accE, di, fmaf(xp2[i], di * di, b2[0]));
}

// ---------------- launch ----------------

extern "C" void kernel_launch(void* const* d_in, const int* in_sizes, int n_in,
                              void* d_out, int out_size, void* d_ws, size_t ws_size,
                              hipStream_t stream) {
  const float* feat = (const float*)d_in[0];
  const int* ei = (const int*)d_in[1];
  const float* ew = (const float*)d_in[2];
  const float* W0 = (const float*)d_in[3];
  const float* b0 = (const float*)d_in[4];
  const float* W1 = (const float*)d_in[5];
  const float* b1 = (const float*)d_in[6];
  const float* W2 = (const float*)d_in[7];
  const float* b2 = (const float*)d_in[8];
  float* out = (float*)d_out;

  const int N_ = in_sizes[0] / NF;
  const int E_ = in_sizes[2];
  const int* row = ei;
  const int* col = ei + E_;

  char* ws = (char*)d_ws;
  size_t off = 0;
  auto alloc = [&](size_t bytes) -> void* {
    void* p = ws + off;
    off = (off + bytes + 255) & ~(size_t)255;
    return p;
  };
  float* bufA  = (float*)alloc((size_t)N_ * NF * 4);   // fp32 agg outputs
  uint*  bufBb = (uint*) alloc((size_t)N_ * NF * 2);   // bf16 GEMM outputs (XP)
  ull*   packed= (ull*)  alloc((size_t)N_ * 8);        // cursor aliases this later
  float* dinv  = (float*)alloc((size_t)N_ * 4);
  float* invs  = (float*)alloc((size_t)N_ * 4);
  int*   rowptr= (int*)  alloc(((size_t)N_ + 1) * 4);
  int*   cnt   = (int*)  alloc((size_t)N_ * 4);
  int*   bsum  = (int*)  alloc(256 * 4);
  int*   bexcl = (int*)  alloc(256 * 4);
  uint*  sEdge = (uint*) alloc((size_t)E_ * 4);
  float* xp2   = (float*)alloc((size_t)N_ * 4);
  int*   cursor= (int*)packed;  // packed is dead after k_finish

  const int nThreads = 256;
  const int gN   = (N_ + nThreads - 1) / nThreads;
  const int gE   = (E_ + nThreads - 1) / nThreads;
  const int gWav = (N_ + 3) / 4;               // one wave per node (64-lane kernels)
  const int gAgg = (N_ + 15) / 16;             // 16 nodes per 256-thread block
  const int nScanBlocks = (N_ + 1023) / 1024;  // <= 256 required

  hipMemsetAsync(packed, 0, (size_t)N_ * 8, stream);
  k_rowsum<<<gWav, nThreads, 0, stream>>>(feat, invs, N_);
  k_edge_pass1<<<gE, nThreads, 0, stream>>>(col, ew, packed, E_);
  k_finish<<<gN, nThreads, 0, stream>>>(packed, dinv, cnt, N_);
  k_scan_local<<<nScanBlocks, nThreads, 0, stream>>>(cnt, rowptr, bsum, N_);
  k_scan_sums<<<1, nThreads, 0, stream>>>(bsum, bexcl, rowptr + N_, nScanBlocks);
  k_scan_add<<<gN, nThreads, 0, stream>>>(rowptr, cursor, bexcl, N_);
  k_edge_scatter<<<gE, nThreads, 0, stream>>>(row, col, ew, dinv, cursor, sEdge, E_);

  const int gGemm = (N_ + 63) / 64;
  // layer 0 (row-normalization folded into GEMM via invs; bf16 XP out)
  k_gemm128<<<gGemm, nThreads, 0, stream>>>(feat, W0, bufBb, N_, invs);
  k_agg128b<<<gAgg, nThreads, 0, stream>>>(bufBb, rowptr, sEdge, dinv, b0, bufA, N_, 1);
  // layer 1
  k_gemm128<<<gGemm, nThreads, 0, stream>>>(bufA, W1, bufBb, N_, nullptr);
  k_agg128b<<<gAgg, nThreads, 0, stream>>>(bufBb, rowptr, sEdge, dinv, b1, bufA, N_, 1);
  // layer 2
  k_gemv<<<gWav, nThreads, 0, stream>>>(bufA, W2, xp2, N_);
  k_agg1<<<gN, nThreads, 0, stream>>>(xp2, rowptr, sEdge, dinv, b2, out, N_);
}

// Round 10
// 483.199 us; speedup vs baseline: 1.7956x; 1.1498x over previous
//
#include <hip/hip_runtime.h>

#define NF 128
typedef unsigned long long ull;
typedef unsigned int uint;

// ---------------- bf16 helpers ----------------

__device__ __forceinline__ float bflo(uint u) { return __uint_as_float(u << 16); }
__device__ __forceinline__ float bfhi(uint u) { return __uint_as_float(u & 0xffff0000u); }
__device__ __forceinline__ uint pack_bf16(float a, float b) {  // RNE
  uint ua = __float_as_uint(a), ub = __float_as_uint(b);
  ua = (ua + 0x7fffu + ((ua >> 16) & 1u)) >> 16;
  ub = (ub + 0x7fffu + ((ub >> 16) & 1u)) & 0xffff0000u;
  return ua | ub;
}

// packed CSC edge entry: [31:17] = norm q15 fixed point, [16:0] = source row
__device__ __forceinline__ uint pack_edge(uint row, float nrm) {
  uint q = __float2uint_rn(nrm * 32768.0f);
  q = q > 32767u ? 32767u : q;
  return (q << 17) | row;
}

// ---- K1: pass1 (degree+count atomic, emits per-edge rank) || rowsum --------
// blocks [0,gE): pass1; [gE, gE+gWav): rowsum. Independent work, one launch.

__global__ __launch_bounds__(256) void k_pre1(const int* __restrict__ col,
                                              const float* __restrict__ w,
                                              ull* __restrict__ packed,
                                              uint* __restrict__ rank, int ne, int gE,
                                              const float* __restrict__ feat,
                                              float* __restrict__ invs, int n) {
  if (blockIdx.x < (uint)gE) {
    int e = blockIdx.x * 256 + threadIdx.x;
    if (e >= ne) return;
    int c = col[e];
    unsigned fix = (unsigned)__float2uint_rn(w[e] * 16777216.0f);  // w * 2^24
    ull old = atomicAdd(&packed[c], ((ull)fix << 32) | 1ull);
    rank[e] = (uint)(old & 0xffffffffu);  // rank of e within column c
  } else {
    int gid = (blockIdx.x - gE) * 256 + threadIdx.x;
    int wave = gid >> 6, lane = gid & 63;
    if (wave >= n) return;
    float2 v = ((const float2*)(feat + (size_t)wave * NF))[lane];
    float s = v.x + v.y;
#pragma unroll
    for (int off = 1; off < 64; off <<= 1) s += __shfl_xor(s, off, 64);
    if (lane == 0) invs[wave] = 1.0f / s;
  }
}

// ---- scan_local fused with finish: reads packed, emits dinv + local scan ---

__global__ __launch_bounds__(256) void k_scan_local(const ull* __restrict__ packed,
                                                    int* __restrict__ excl,
                                                    int* __restrict__ bsum,
                                                    float* __restrict__ dinv, int n) {
  __shared__ int sd[256];
  int tid = threadIdx.x;
  int idx = blockIdx.x * 1024 + tid * 4;
  int4 v = {0, 0, 0, 0};
  const float k24 = 1.0f / 16777216.0f;
  if (idx + 4 <= n) {
    ull p0 = packed[idx], p1 = packed[idx + 1], p2 = packed[idx + 2], p3 = packed[idx + 3];
    v.x = (int)(uint)p0; v.y = (int)(uint)p1; v.z = (int)(uint)p2; v.w = (int)(uint)p3;
    float4 dv;
    dv.x = rsqrtf((float)(uint)(p0 >> 32) * k24 + 1.0f);
    dv.y = rsqrtf((float)(uint)(p1 >> 32) * k24 + 1.0f);
    dv.z = rsqrtf((float)(uint)(p2 >> 32) * k24 + 1.0f);
    dv.w = rsqrtf((float)(uint)(p3 >> 32) * k24 + 1.0f);
    *(float4*)&dinv[idx] = dv;
  } else {
    for (int k = 0; k < 4; ++k) {
      if (idx + k < n) {
        ull p = packed[idx + k];
        ((int*)&v)[k] = (int)(uint)p;
        dinv[idx + k] = rsqrtf((float)(uint)(p >> 32) * k24 + 1.0f);
      }
    }
  }
  int tsum = v.x + v.y + v.z + v.w;
  sd[tid] = tsum;
  __syncthreads();
  for (int off = 1; off < 256; off <<= 1) {
    int t = (tid >= off) ? sd[tid - off] : 0;
    __syncthreads();
    sd[tid] += t;
    __syncthreads();
  }
  int texcl = sd[tid] - tsum;
  if (tid == 255) bsum[blockIdx.x] = sd[255];
  int4 w;
  w.x = texcl; w.y = texcl + v.x; w.z = texcl + v.x + v.y; w.w = texcl + v.x + v.y + v.z;
  if (idx + 4 <= n) {
    *(int4*)&excl[idx] = w;
  } else {
    if (idx < n)     excl[idx] = w.x;
    if (idx + 1 < n) excl[idx + 1] = w.y;
    if (idx + 2 < n) excl[idx + 2] = w.z;
    if (idx + 3 < n) excl[idx + 3] = w.w;
  }
}

__global__ __launch_bounds__(256) void k_scan_sums(const int* __restrict__ bsum,
                                                   int* __restrict__ bexcl,
                                                   int* __restrict__ rowptr_end, int nb) {
  __shared__ int sd[256];
  int tid = threadIdx.x;
  int v = (tid < nb) ? bsum[tid] : 0;
  sd[tid] = v;
  __syncthreads();
  for (int off = 1; off < 256; off <<= 1) {
    int t = (tid >= off) ? sd[tid - off] : 0;
    __syncthreads();
    sd[tid] += t;
    __syncthreads();
  }
  if (tid < nb) bexcl[tid] = sd[tid] - v;
  if (tid == 255) rowptr_end[0] = sd[255];
}

__global__ __launch_bounds__(256) void k_scan_add(int* __restrict__ rowptr,
                                                  const int* __restrict__ bexcl, int n) {
  int i = blockIdx.x * 256 + threadIdx.x;
  if (i >= n) return;
  rowptr[i] += bexcl[i >> 10];
}

// ---------------- GEMM body (shared by fused + standalone kernels) ----------

__device__ __forceinline__ void gemm_body(const float* __restrict__ X,
                                          const float* __restrict__ W,
                                          uint* __restrict__ Yb, int n,
                                          const float* __restrict__ scale,
                                          int bid, int tid,
                                          float* Ws, float* Xs) {
  for (int i = tid * 4; i < 128 * 128; i += 256 * 4)
    *(float4*)&Ws[i] = *(const float4*)&W[i];

  int r0 = bid * 64;
  int tcol = tid & 15, trow = tid >> 4;
  float acc[4][8] = {};

  for (int kc = 0; kc < 128; kc += 32) {
    __syncthreads();
    {
      int rr = tid >> 2;
      int cc = (tid & 3) * 8;
      int grow = r0 + rr;
      if (grow >= n) grow = n - 1;
      float sc = scale ? scale[grow] : 1.0f;
      const float* src = X + (size_t)grow * NF + kc + cc;
      float4 a = *(const float4*)src;
      float4 b = *(const float4*)(src + 4);
      a.x *= sc; a.y *= sc; a.z *= sc; a.w *= sc;
      b.x *= sc; b.y *= sc; b.z *= sc; b.w *= sc;
      *(float4*)&Xs[rr * 36 + cc] = a;
      *(float4*)&Xs[rr * 36 + cc + 4] = b;
    }
    __syncthreads();
#pragma unroll
    for (int k4 = 0; k4 < 32; k4 += 4) {
      float4 xv[4];
#pragma unroll
      for (int i = 0; i < 4; i++)
        xv[i] = *(const float4*)&Xs[(trow * 4 + i) * 36 + k4];
#pragma unroll
      for (int kk = 0; kk < 4; kk++) {
        float4 w0 = *(const float4*)&Ws[(kc + k4 + kk) * 128 + tcol * 4];
        float4 w1 = *(const float4*)&Ws[(kc + k4 + kk) * 128 + 64 + tcol * 4];
#pragma unroll
        for (int i = 0; i < 4; i++) {
          float xx = ((const float*)&xv[i])[kk];
          acc[i][0] = fmaf(xx, w0.x, acc[i][0]);
          acc[i][1] = fmaf(xx, w0.y, acc[i][1]);
          acc[i][2] = fmaf(xx, w0.z, acc[i][2]);
          acc[i][3] = fmaf(xx, w0.w, acc[i][3]);
          acc[i][4] = fmaf(xx, w1.x, acc[i][4]);
          acc[i][5] = fmaf(xx, w1.y, acc[i][5]);
          acc[i][6] = fmaf(xx, w1.z, acc[i][6]);
          acc[i][7] = fmaf(xx, w1.w, acc[i][7]);
        }
      }
    }
  }
#pragma unroll
  for (int i = 0; i < 4; i++) {
    int gr = r0 + trow * 4 + i;
    if (gr < n) {
      uint2 p0 = {pack_bf16(acc[i][0], acc[i][1]), pack_bf16(acc[i][2], acc[i][3])};
      uint2 p1 = {pack_bf16(acc[i][4], acc[i][5]), pack_bf16(acc[i][6], acc[i][7])};
      *(uint2*)&Yb[(size_t)gr * 64 + tcol * 2] = p0;
      *(uint2*)&Yb[(size_t)gr * 64 + 32 + tcol * 2] = p1;
    }
  }
}

// ---- K2: atomic-free CSC scatter || GEMM0 ----------------------------------
// blocks [0,gE): scatter (pos = rowptr[c] + rank[e], ONE random store);
// blocks [gE, gE+gGemm): layer-0 GEMM with row-norm folded in.

__global__ __launch_bounds__(256, 2) void k_sc_gemm(const int* __restrict__ row,
                                                    const int* __restrict__ col,
                                                    const float* __restrict__ w,
                                                    const float* __restrict__ dinv,
                                                    const int* __restrict__ rowptr,
                                                    const uint* __restrict__ rank,
                                                    uint* __restrict__ sEdge, int ne, int gE,
                                                    const float* __restrict__ X,
                                                    const float* __restrict__ W0,
                                                    const float* __restrict__ invs,
                                                    uint* __restrict__ Yb, int n) {
  __shared__ float Ws[128 * 128];
  __shared__ float Xs[64 * 36];
  if (blockIdx.x < (uint)gE) {
    int e = blockIdx.x * 256 + threadIdx.x;
    if (e >= ne) return;
    int r = row[e], c = col[e];
    int pos = rowptr[c] + (int)rank[e];
    float nrm = dinv[r] * w[e];  // dinv[c] applied in the agg kernel; nrm < 1.0
    sEdge[pos] = pack_edge((uint)r, nrm);
    return;
  }
  gemm_body(X, W0, Yb, n, invs, blockIdx.x - gE, threadIdx.x, Ws, Xs);
}

// standalone GEMM (layer 1)
__global__ __launch_bounds__(256, 2) void k_gemm128(const float* __restrict__ X,
                                                    const float* __restrict__ W,
                                                    uint* __restrict__ Yb, int n) {
  __shared__ float Ws[128 * 128];
  __shared__ float Xs[64 * 36];
  gemm_body(X, W, Yb, n, nullptr, blockIdx.x, threadIdx.x, Ws, Xs);
}

// ---------------- pull aggregation, H=128, bf16 gathers ----------------
// 4 nodes per wave (16 lanes x uint4 = 256B bf16 row); 8-edge chunks -> 32
// gathers in flight per wave. fp32 accumulate.

#define AGG_PROLOGUE \
  int gid = blockIdx.x * 256 + threadIdx.x; \
  int i = gid >> 4; \
  int lane = gid & 15; \
  if (i >= n) return; \
  float di = dinv[i]; \
  uint4 xv = ((const uint4*)XPb)[(size_t)i * 16 + lane]; \
  int s = rowptr[i], e = rowptr[i + 1]; \
  float acc[8] = {0.f, 0.f, 0.f, 0.f, 0.f, 0.f, 0.f, 0.f}; \
  int j = s;

#define GATHER(en, g) \
  uint4 g = ((const uint4*)XPb)[(size_t)((en) & 0x1FFFFu) * 16 + lane];
#define ACCUM(en, g) { \
  float nr = (float)((en) >> 17) * (1.0f / 32768.0f); \
  acc[0] = fmaf(bflo(g.x), nr, acc[0]); acc[1] = fmaf(bfhi(g.x), nr, acc[1]); \
  acc[2] = fmaf(bflo(g.y), nr, acc[2]); acc[3] = fmaf(bfhi(g.y), nr, acc[3]); \
  acc[4] = fmaf(bflo(g.z), nr, acc[4]); acc[5] = fmaf(bfhi(g.z), nr, acc[5]); \
  acc[6] = fmaf(bflo(g.w), nr, acc[6]); acc[7] = fmaf(bfhi(g.w), nr, acc[7]); }

#define AGG_EDGE_LOOP \
  for (; j + 8 <= e; j += 8) { \
    uint e0 = sEdge[j],     e1 = sEdge[j + 1], e2 = sEdge[j + 2], e3 = sEdge[j + 3]; \
    uint e4 = sEdge[j + 4], e5 = sEdge[j + 5], e6 = sEdge[j + 6], e7 = sEdge[j + 7]; \
    GATHER(e0, g0) GATHER(e1, g1) GATHER(e2, g2) GATHER(e3, g3) \
    GATHER(e4, g4) GATHER(e5, g5) GATHER(e6, g6) GATHER(e7, g7) \
    ACCUM(e0, g0) ACCUM(e1, g1) ACCUM(e2, g2) ACCUM(e3, g3) \
    ACCUM(e4, g4) ACCUM(e5, g5) ACCUM(e6, g6) ACCUM(e7, g7) \
  } \
  if (j + 4 <= e) { \
    uint e0 = sEdge[j], e1 = sEdge[j + 1], e2 = sEdge[j + 2], e3 = sEdge[j + 3]; \
    GATHER(e0, g0) GATHER(e1, g1) GATHER(e2, g2) GATHER(e3, g3) \
    ACCUM(e0, g0) ACCUM(e1, g1) ACCUM(e2, g2) ACCUM(e3, g3) \
    j += 4; \
  } \
  for (; j < e; ++j) { \
    uint e0 = sEdge[j]; \
    GATHER(e0, g0) \
    ACCUM(e0, g0) \
  }

#define AGG_FINISH(o0, o1, bias) \
  float sn = di * di; \
  float4 o0, o1; \
  { \
    float4 bA = ((const float4*)bias)[lane * 2]; \
    float4 bB = ((const float4*)bias)[lane * 2 + 1]; \
    o0.x = fmaf(acc[0], di, fmaf(bflo(xv.x), sn, bA.x)); \
    o0.y = fmaf(acc[1], di, fmaf(bfhi(xv.x), sn, bA.y)); \
    o0.z = fmaf(acc[2], di, fmaf(bflo(xv.y), sn, bA.z)); \
    o0.w = fmaf(acc[3], di, fmaf(bfhi(xv.y), sn, bA.w)); \
    o1.x = fmaf(acc[4], di, fmaf(bflo(xv.z), sn, bB.x)); \
    o1.y = fmaf(acc[5], di, fmaf(bfhi(xv.z), sn, bB.y)); \
    o1.z = fmaf(acc[6], di, fmaf(bflo(xv.w), sn, bB.z)); \
    o1.w = fmaf(acc[7], di, fmaf(bfhi(xv.w), sn, bB.w)); \
    o0.x = fmaxf(o0.x, 0.f); o0.y = fmaxf(o0.y, 0.f); \
    o0.z = fmaxf(o0.z, 0.f); o0.w = fmaxf(o0.w, 0.f); \
    o1.x = fmaxf(o1.x, 0.f); o1.y = fmaxf(o1.y, 0.f); \
    o1.z = fmaxf(o1.z, 0.f); o1.w = fmaxf(o1.w, 0.f); \
  }

// layer-0 agg: writes fp32 activations (relu)
__global__ __launch_bounds__(256) void k_agg128b(const uint* __restrict__ XPb,
                                                 const int* __restrict__ rowptr,
                                                 const uint* __restrict__ sEdge,
                                                 const float* __restrict__ dinv,
                                                 const float* __restrict__ bias,
                                                 float* __restrict__ Y, int n) {
  AGG_PROLOGUE
  AGG_EDGE_LOOP
  AGG_FINISH(o0, o1, bias)
  ((float4*)(Y + (size_t)i * NF))[lane * 2] = o0;
  ((float4*)(Y + (size_t)i * NF))[lane * 2 + 1] = o1;
}

// layer-1 agg fused with W2 GEMV: writes only xp2[i] (no 51MB activation write)
__global__ __launch_bounds__(256) void k_agg_gemv(const uint* __restrict__ XPb,
                                                  const int* __restrict__ rowptr,
                                                  const uint* __restrict__ sEdge,
                                                  const float* __restrict__ dinv,
                                                  const float* __restrict__ bias,
                                                  const float* __restrict__ w2,
                                                  float* __restrict__ xp2, int n) {
  AGG_PROLOGUE
  AGG_EDGE_LOOP
  AGG_FINISH(o0, o1, bias)
  float4 wA = ((const float4*)w2)[lane * 2];
  float4 wB = ((const float4*)w2)[lane * 2 + 1];
  float sdot = o0.x * wA.x + o0.y * wA.y + o0.z * wA.z + o0.w * wA.w +
               o1.x * wB.x + o1.y * wB.y + o1.z * wB.z + o1.w * wB.w;
  sdot += __shfl_xor(sdot, 1, 64);
  sdot += __shfl_xor(sdot, 2, 64);
  sdot += __shfl_xor(sdot, 4, 64);
  sdot += __shfl_xor(sdot, 8, 64);
  if (lane == 0) xp2[i] = sdot;
}

// ---------------- layer 2: scalar aggregation ----------------

__global__ __launch_bounds__(256) void k_agg1(const float* __restrict__ xp2,
                                              const int* __restrict__ rowptr,
                                              const uint* __restrict__ sEdge,
                                              const float* __restrict__ dinv,
                                              const float* __restrict__ b2,
                                              float* __restrict__ out, int n) {
  int i = blockIdx.x * 256 + threadIdx.x;
  if (i >= n) return;
  float di = dinv[i];
  float accE = 0.0f;
  int s = rowptr[i], e = rowptr[i + 1];
  int j = s;
  for (; j + 4 <= e; j += 4) {
    uint e0 = sEdge[j], e1 = sEdge[j + 1], e2 = sEdge[j + 2], e3 = sEdge[j + 3];
    float v0 = xp2[e0 & 0x1FFFFu], v1 = xp2[e1 & 0x1FFFFu];
    float v2 = xp2[e2 & 0x1FFFFu], v3 = xp2[e3 & 0x1FFFFu];
    accE = fmaf(v0, (float)(e0 >> 17) * (1.0f / 32768.0f), accE);
    accE = fmaf(v1, (float)(e1 >> 17) * (1.0f / 32768.0f), accE);
    accE = fmaf(v2, (float)(e2 >> 17) * (1.0f / 32768.0f), accE);
    accE = fmaf(v3, (float)(e3 >> 17) * (1.0f / 32768.0f), accE);
  }
  for (; j < e; ++j) {
    uint e0 = sEdge[j];
    accE = fmaf(xp2[e0 & 0x1FFFFu], (float)(e0 >> 17) * (1.0f / 32768.0f), accE);
  }
  out[i] = fmaf(accE, di, fmaf(xp2[i], di * di, b2[0]));
}

// ---------------- launch ----------------

extern "C" void kernel_launch(void* const* d_in, const int* in_sizes, int n_in,
                              void* d_out, int out_size, void* d_ws, size_t ws_size,
                              hipStream_t stream) {
  const float* feat = (const float*)d_in[0];
  const int* ei = (const int*)d_in[1];
  const float* ew = (const float*)d_in[2];
  const float* W0 = (const float*)d_in[3];
  const float* b0 = (const float*)d_in[4];
  const float* W1 = (const float*)d_in[5];
  const float* b1 = (const float*)d_in[6];
  const float* W2 = (const float*)d_in[7];
  const float* b2 = (const float*)d_in[8];
  float* out = (float*)d_out;

  const int N_ = in_sizes[0] / NF;
  const int E_ = in_sizes[2];
  const int* row = ei;
  const int* col = ei + E_;

  char* ws = (char*)d_ws;
  size_t off = 0;
  auto alloc = [&](size_t bytes) -> void* {
    void* p = ws + off;
    off = (off + bytes + 255) & ~(size_t)255;
    return p;
  };
  float* bufA  = (float*)alloc((size_t)N_ * NF * 4);   // fp32 layer-0 activations
  uint*  bufBb = (uint*) alloc((size_t)N_ * NF * 2);   // bf16 GEMM outputs (XP)
  ull*   packed= (ull*)  alloc((size_t)N_ * 8);
  float* dinv  = (float*)alloc((size_t)N_ * 4);
  float* invs  = (float*)alloc((size_t)N_ * 4);
  int*   rowptr= (int*)  alloc(((size_t)N_ + 1) * 4);
  int*   bsum  = (int*)  alloc(256 * 4);
  int*   bexcl = (int*)  alloc(256 * 4);
  uint*  rank  = (uint*) alloc((size_t)E_ * 4);
  uint*  sEdge = (uint*) alloc((size_t)E_ * 4);
  float* xp2   = (float*)alloc((size_t)N_ * 4);

  const int nThreads = 256;
  const int gN   = (N_ + nThreads - 1) / nThreads;
  const int gE   = (E_ + nThreads - 1) / nThreads;
  const int gWav = (N_ + 3) / 4;               // one wave per node (rowsum)
  const int gAgg = (N_ + 15) / 16;             // 16 nodes per 256-thread block
  const int gGemm = (N_ + 63) / 64;
  const int nScanBlocks = (N_ + 1023) / 1024;  // <= 256 required

  hipMemsetAsync(packed, 0, (size_t)N_ * 8, stream);
  // K1: pass1 (atomics + rank) || rowsum
  k_pre1<<<gE + gWav, nThreads, 0, stream>>>(col, ew, packed, rank, E_, gE,
                                             feat, invs, N_);
  // scan (finish fused into scan_local)
  k_scan_local<<<nScanBlocks, nThreads, 0, stream>>>(packed, rowptr, bsum, dinv, N_);
  k_scan_sums<<<1, nThreads, 0, stream>>>(bsum, bexcl, rowptr + N_, nScanBlocks);
  k_scan_add<<<gN, nThreads, 0, stream>>>(rowptr, bexcl, N_);
  // K2: atomic-free scatter || layer-0 GEMM (row-norm folded via invs)
  k_sc_gemm<<<gE + gGemm, nThreads, 0, stream>>>(row, col, ew, dinv, rowptr, rank,
                                                 sEdge, E_, gE,
                                                 feat, W0, invs, bufBb, N_);
  // layer 0 aggregation -> fp32 activations
  k_agg128b<<<gAgg, nThreads, 0, stream>>>(bufBb, rowptr, sEdge, dinv, b0, bufA, N_);
  // layer 1 GEMM
  k_gemm128<<<gGemm, nThreads, 0, stream>>>(bufA, W1, bufBb, N_);
  // layer 1 aggregation fused with W2 GEMV -> xp2 only
  k_agg_gemv<<<gAgg, nThreads, 0, stream>>>(bufBb, rowptr, sEdge, dinv, b1, W2, xp2, N_);
  // layer 2 aggregation
  k_agg1<<<gN, nThreads, 0, stream>>>(xp2, rowptr, sEdge, dinv, b2, out, N_);
}

// Round 11
// 478.725 us; speedup vs baseline: 1.8124x; 1.0093x over previous
//
#include <hip/hip_runtime.h>

#define NF 128
typedef unsigned long long ull;
typedef unsigned int uint;

// ---------------- bf16 helpers ----------------

__device__ __forceinline__ float bflo(uint u) { return __uint_as_float(u << 16); }
__device__ __forceinline__ float bfhi(uint u) { return __uint_as_float(u & 0xffff0000u); }
__device__ __forceinline__ uint pack_bf16(float a, float b) {  // RNE
  uint ua = __float_as_uint(a), ub = __float_as_uint(b);
  ua = (ua + 0x7fffu + ((ua >> 16) & 1u)) >> 16;
  ub = (ub + 0x7fffu + ((ub >> 16) & 1u)) & 0xffff0000u;
  return ua | ub;
}

// packed CSC edge entry: [31:17] = norm q15 fixed point, [16:0] = source row
__device__ __forceinline__ uint pack_edge(uint row, float nrm) {
  uint q = __float2uint_rn(nrm * 32768.0f);
  q = q > 32767u ? 32767u : q;
  return (q << 17) | row;
}

// ---- K1: pass1 (degree+count atomic, emits per-edge rank) || rowsum --------

__global__ __launch_bounds__(256) void k_pre1(const int* __restrict__ col,
                                              const float* __restrict__ w,
                                              ull* __restrict__ packed,
                                              uint* __restrict__ rank, int ne, int gE,
                                              const float* __restrict__ feat,
                                              float* __restrict__ invs, int n) {
  if (blockIdx.x < (uint)gE) {
    int e = blockIdx.x * 256 + threadIdx.x;
    if (e >= ne) return;
    int c = col[e];
    unsigned fix = (unsigned)__float2uint_rn(w[e] * 16777216.0f);  // w * 2^24
    ull old = atomicAdd(&packed[c], ((ull)fix << 32) | 1ull);
    rank[e] = (uint)(old & 0xffffffffu);  // rank of e within column c
  } else {
    int gid = (blockIdx.x - gE) * 256 + threadIdx.x;
    int wave = gid >> 6, lane = gid & 63;
    if (wave >= n) return;
    float2 v = ((const float2*)(feat + (size_t)wave * NF))[lane];
    float s = v.x + v.y;
#pragma unroll
    for (int off = 1; off < 64; off <<= 1) s += __shfl_xor(s, off, 64);
    if (lane == 0) invs[wave] = 1.0f / s;
  }
}

// ---- scan_local fused with finish: reads packed, emits dinv + local scan ---

__global__ __launch_bounds__(256) void k_scan_local(const ull* __restrict__ packed,
                                                    int* __restrict__ excl,
                                                    int* __restrict__ bsum,
                                                    float* __restrict__ dinv, int n) {
  __shared__ int sd[256];
  int tid = threadIdx.x;
  int idx = blockIdx.x * 1024 + tid * 4;
  int4 v = {0, 0, 0, 0};
  const float k24 = 1.0f / 16777216.0f;
  if (idx + 4 <= n) {
    ull p0 = packed[idx], p1 = packed[idx + 1], p2 = packed[idx + 2], p3 = packed[idx + 3];
    v.x = (int)(uint)p0; v.y = (int)(uint)p1; v.z = (int)(uint)p2; v.w = (int)(uint)p3;
    float4 dv;
    dv.x = rsqrtf((float)(uint)(p0 >> 32) * k24 + 1.0f);
    dv.y = rsqrtf((float)(uint)(p1 >> 32) * k24 + 1.0f);
    dv.z = rsqrtf((float)(uint)(p2 >> 32) * k24 + 1.0f);
    dv.w = rsqrtf((float)(uint)(p3 >> 32) * k24 + 1.0f);
    *(float4*)&dinv[idx] = dv;
  } else {
    for (int k = 0; k < 4; ++k) {
      if (idx + k < n) {
        ull p = packed[idx + k];
        ((int*)&v)[k] = (int)(uint)p;
        dinv[idx + k] = rsqrtf((float)(uint)(p >> 32) * k24 + 1.0f);
      }
    }
  }
  int tsum = v.x + v.y + v.z + v.w;
  sd[tid] = tsum;
  __syncthreads();
  for (int off = 1; off < 256; off <<= 1) {
    int t = (tid >= off) ? sd[tid - off] : 0;
    __syncthreads();
    sd[tid] += t;
    __syncthreads();
  }
  int texcl = sd[tid] - tsum;
  if (tid == 255) bsum[blockIdx.x] = sd[255];
  int4 w;
  w.x = texcl; w.y = texcl + v.x; w.z = texcl + v.x + v.y; w.w = texcl + v.x + v.y + v.z;
  if (idx + 4 <= n) {
    *(int4*)&excl[idx] = w;
  } else {
    if (idx < n)     excl[idx] = w.x;
    if (idx + 1 < n) excl[idx + 1] = w.y;
    if (idx + 2 < n) excl[idx + 2] = w.z;
    if (idx + 3 < n) excl[idx + 3] = w.w;
  }
}

__global__ __launch_bounds__(256) void k_scan_sums(const int* __restrict__ bsum,
                                                   int* __restrict__ bexcl,
                                                   int* __restrict__ rowptr_end, int nb) {
  __shared__ int sd[256];
  int tid = threadIdx.x;
  int v = (tid < nb) ? bsum[tid] : 0;
  sd[tid] = v;
  __syncthreads();
  for (int off = 1; off < 256; off <<= 1) {
    int t = (tid >= off) ? sd[tid - off] : 0;
    __syncthreads();
    sd[tid] += t;
    __syncthreads();
  }
  if (tid < nb) bexcl[tid] = sd[tid] - v;
  if (tid == 255) rowptr_end[0] = sd[255];
}

__global__ __launch_bounds__(256) void k_scan_add(int* __restrict__ rowptr,
                                                  const int* __restrict__ bexcl, int n) {
  int i = blockIdx.x * 256 + threadIdx.x;
  if (i >= n) return;
  rowptr[i] += bexcl[i >> 10];
}

// ---- 64x64 GEMM body: block computes rows rb*64.., cols ch*64.. ------------
// LDS: Ws 128x64 f32 (32KB) + Xs 64x36 (9KB) = 42KB -> 3 blocks/CU.

__device__ __forceinline__ void gemm64_body(const float* __restrict__ X,
                                            const float* __restrict__ W,
                                            uint* __restrict__ Yb, int n,
                                            const float* __restrict__ scale,
                                            int rb, int ch, int tid,
                                            float* Ws, float* Xs) {
  {
    const float* Wc = W + ch * 64;
    for (int i = tid; i < 2048; i += 256) {
      int k = i >> 4, c4 = (i & 15) << 2;
      *(float4*)&Ws[k * 64 + c4] = *(const float4*)&Wc[k * 128 + c4];
    }
  }
  int r0 = rb * 64;
  int tcol = tid & 15, trow = tid >> 4;
  float acc[4][4] = {};

  for (int kc = 0; kc < 128; kc += 32) {
    __syncthreads();
    {
      int rr = tid >> 2;
      int cc = (tid & 3) * 8;
      int grow = r0 + rr;
      if (grow >= n) grow = n - 1;
      float sc = scale ? scale[grow] : 1.0f;
      const float* src = X + (size_t)grow * NF + kc + cc;
      float4 a = *(const float4*)src;
      float4 b = *(const float4*)(src + 4);
      a.x *= sc; a.y *= sc; a.z *= sc; a.w *= sc;
      b.x *= sc; b.y *= sc; b.z *= sc; b.w *= sc;
      *(float4*)&Xs[rr * 36 + cc] = a;
      *(float4*)&Xs[rr * 36 + cc + 4] = b;
    }
    __syncthreads();
#pragma unroll
    for (int k4 = 0; k4 < 32; k4 += 4) {
      float4 xv[4];
#pragma unroll
      for (int i = 0; i < 4; i++)
        xv[i] = *(const float4*)&Xs[(trow * 4 + i) * 36 + k4];
#pragma unroll
      for (int kk = 0; kk < 4; kk++) {
        float4 w0 = *(const float4*)&Ws[(kc + k4 + kk) * 64 + tcol * 4];
#pragma unroll
        for (int i = 0; i < 4; i++) {
          float xx = ((const float*)&xv[i])[kk];
          acc[i][0] = fmaf(xx, w0.x, acc[i][0]);
          acc[i][1] = fmaf(xx, w0.y, acc[i][1]);
          acc[i][2] = fmaf(xx, w0.z, acc[i][2]);
          acc[i][3] = fmaf(xx, w0.w, acc[i][3]);
        }
      }
    }
  }
#pragma unroll
  for (int i = 0; i < 4; i++) {
    int gr = r0 + trow * 4 + i;
    if (gr < n) {
      uint2 p = {pack_bf16(acc[i][0], acc[i][1]), pack_bf16(acc[i][2], acc[i][3])};
      *(uint2*)&Yb[(size_t)gr * 64 + ch * 32 + tcol * 2] = p;
    }
  }
}

// ---- K2: atomic-free CSC scatter || 64x64 GEMM0 ----------------------------

__global__ __launch_bounds__(256, 3) void k_sc_gemm(const int* __restrict__ row,
                                                    const int* __restrict__ col,
                                                    const float* __restrict__ w,
                                                    const float* __restrict__ dinv,
                                                    const int* __restrict__ rowptr,
                                                    const uint* __restrict__ rank,
                                                    uint* __restrict__ sEdge, int ne, int gE,
                                                    const float* __restrict__ X,
                                                    const float* __restrict__ W0,
                                                    const float* __restrict__ invs,
                                                    uint* __restrict__ Yb, int n) {
  __shared__ float Ws[128 * 64];
  __shared__ float Xs[64 * 36];
  if (blockIdx.x < (uint)gE) {
    int e = blockIdx.x * 256 + threadIdx.x;
    if (e >= ne) return;
    int r = row[e], c = col[e];
    int pos = rowptr[c] + (int)rank[e];
    float nrm = dinv[r] * w[e];  // dinv[c] applied in the agg kernel; nrm < 1.0
    sEdge[pos] = pack_edge((uint)r, nrm);
    return;
  }
  int bid = blockIdx.x - gE;
  gemm64_body(X, W0, Yb, n, invs, bid >> 1, bid & 1, threadIdx.x, Ws, Xs);
}

// standalone GEMM (layer 1), full 128-col body, W fully in LDS
__global__ __launch_bounds__(256, 2) void k_gemm128(const float* __restrict__ X,
                                                    const float* __restrict__ W,
                                                    uint* __restrict__ Yb, int n) {
  __shared__ float Ws[128 * 128];
  __shared__ float Xs[64 * 36];
  const int tid = threadIdx.x;
  for (int i = tid * 4; i < 128 * 128; i += 256 * 4)
    *(float4*)&Ws[i] = *(const float4*)&W[i];

  int r0 = blockIdx.x * 64;
  int tcol = tid & 15, trow = tid >> 4;
  float acc[4][8] = {};

  for (int kc = 0; kc < 128; kc += 32) {
    __syncthreads();
    {
      int rr = tid >> 2;
      int cc = (tid & 3) * 8;
      int grow = r0 + rr;
      if (grow >= n) grow = n - 1;
      const float* src = X + (size_t)grow * NF + kc + cc;
      float4 a = *(const float4*)src;
      float4 b = *(const float4*)(src + 4);
      *(float4*)&Xs[rr * 36 + cc] = a;
      *(float4*)&Xs[rr * 36 + cc + 4] = b;
    }
    __syncthreads();
#pragma unroll
    for (int k4 = 0; k4 < 32; k4 += 4) {
      float4 xv[4];
#pragma unroll
      for (int i = 0; i < 4; i++)
        xv[i] = *(const float4*)&Xs[(trow * 4 + i) * 36 + k4];
#pragma unroll
      for (int kk = 0; kk < 4; kk++) {
        float4 w0 = *(const float4*)&Ws[(kc + k4 + kk) * 128 + tcol * 4];
        float4 w1 = *(const float4*)&Ws[(kc + k4 + kk) * 128 + 64 + tcol * 4];
#pragma unroll
        for (int i = 0; i < 4; i++) {
          float xx = ((const float*)&xv[i])[kk];
          acc[i][0] = fmaf(xx, w0.x, acc[i][0]);
          acc[i][1] = fmaf(xx, w0.y, acc[i][1]);
          acc[i][2] = fmaf(xx, w0.z, acc[i][2]);
          acc[i][3] = fmaf(xx, w0.w, acc[i][3]);
          acc[i][4] = fmaf(xx, w1.x, acc[i][4]);
          acc[i][5] = fmaf(xx, w1.y, acc[i][5]);
          acc[i][6] = fmaf(xx, w1.z, acc[i][6]);
          acc[i][7] = fmaf(xx, w1.w, acc[i][7]);
        }
      }
    }
  }
#pragma unroll
  for (int i = 0; i < 4; i++) {
    int gr = r0 + trow * 4 + i;
    if (gr < n) {
      uint2 p0 = {pack_bf16(acc[i][0], acc[i][1]), pack_bf16(acc[i][2], acc[i][3])};
      uint2 p1 = {pack_bf16(acc[i][4], acc[i][5]), pack_bf16(acc[i][6], acc[i][7])};
      *(uint2*)&Yb[(size_t)gr * 64 + tcol * 2] = p0;
      *(uint2*)&Yb[(size_t)gr * 64 + 32 + tcol * 2] = p1;
    }
  }
}

// ---------------- pull aggregation, H=128, bf16 gathers ----------------

#define AGG_PROLOGUE \
  int gid = blockIdx.x * 256 + threadIdx.x; \
  int i = gid >> 4; \
  int lane = gid & 15; \
  if (i >= n) return; \
  float di = dinv[i]; \
  uint4 xv = ((const uint4*)XPb)[(size_t)i * 16 + lane]; \
  int s = rowptr[i], e = rowptr[i + 1]; \
  float acc[8] = {0.f, 0.f, 0.f, 0.f, 0.f, 0.f, 0.f, 0.f}; \
  int j = s;

#define GATHER(en, g) \
  uint4 g = ((const uint4*)XPb)[(size_t)((en) & 0x1FFFFu) * 16 + lane];
#define ACCUM(en, g) { \
  float nr = (float)((en) >> 17) * (1.0f / 32768.0f); \
  acc[0] = fmaf(bflo(g.x), nr, acc[0]); acc[1] = fmaf(bfhi(g.x), nr, acc[1]); \
  acc[2] = fmaf(bflo(g.y), nr, acc[2]); acc[3] = fmaf(bfhi(g.y), nr, acc[3]); \
  acc[4] = fmaf(bflo(g.z), nr, acc[4]); acc[5] = fmaf(bfhi(g.z), nr, acc[5]); \
  acc[6] = fmaf(bflo(g.w), nr, acc[6]); acc[7] = fmaf(bfhi(g.w), nr, acc[7]); }

#define AGG_EDGE_LOOP \
  for (; j + 8 <= e; j += 8) { \
    uint e0 = sEdge[j],     e1 = sEdge[j + 1], e2 = sEdge[j + 2], e3 = sEdge[j + 3]; \
    uint e4 = sEdge[j + 4], e5 = sEdge[j + 5], e6 = sEdge[j + 6], e7 = sEdge[j + 7]; \
    GATHER(e0, g0) GATHER(e1, g1) GATHER(e2, g2) GATHER(e3, g3) \
    GATHER(e4, g4) GATHER(e5, g5) GATHER(e6, g6) GATHER(e7, g7) \
    ACCUM(e0, g0) ACCUM(e1, g1) ACCUM(e2, g2) ACCUM(e3, g3) \
    ACCUM(e4, g4) ACCUM(e5, g5) ACCUM(e6, g6) ACCUM(e7, g7) \
  } \
  if (j + 4 <= e) { \
    uint e0 = sEdge[j], e1 = sEdge[j + 1], e2 = sEdge[j + 2], e3 = sEdge[j + 3]; \
    GATHER(e0, g0) GATHER(e1, g1) GATHER(e2, g2) GATHER(e3, g3) \
    ACCUM(e0, g0) ACCUM(e1, g1) ACCUM(e2, g2) ACCUM(e3, g3) \
    j += 4; \
  } \
  for (; j < e; ++j) { \
    uint e0 = sEdge[j]; \
    GATHER(e0, g0) \
    ACCUM(e0, g0) \
  }

#define AGG_FINISH(o0, o1, bias) \
  float sn = di * di; \
  float4 o0, o1; \
  { \
    float4 bA = ((const float4*)bias)[lane * 2]; \
    float4 bB = ((const float4*)bias)[lane * 2 + 1]; \
    o0.x = fmaf(acc[0], di, fmaf(bflo(xv.x), sn, bA.x)); \
    o0.y = fmaf(acc[1], di, fmaf(bfhi(xv.x), sn, bA.y)); \
    o0.z = fmaf(acc[2], di, fmaf(bflo(xv.y), sn, bA.z)); \
    o0.w = fmaf(acc[3], di, fmaf(bfhi(xv.y), sn, bA.w)); \
    o1.x = fmaf(acc[4], di, fmaf(bflo(xv.z), sn, bB.x)); \
    o1.y = fmaf(acc[5], di, fmaf(bfhi(xv.z), sn, bB.y)); \
    o1.z = fmaf(acc[6], di, fmaf(bflo(xv.w), sn, bB.z)); \
    o1.w = fmaf(acc[7], di, fmaf(bfhi(xv.w), sn, bB.w)); \
    o0.x = fmaxf(o0.x, 0.f); o0.y = fmaxf(o0.y, 0.f); \
    o0.z = fmaxf(o0.z, 0.f); o0.w = fmaxf(o0.w, 0.f); \
    o1.x = fmaxf(o1.x, 0.f); o1.y = fmaxf(o1.y, 0.f); \
    o1.z = fmaxf(o1.z, 0.f); o1.w = fmaxf(o1.w, 0.f); \
  }

// layer-0 agg: writes fp32 activations (relu)
__global__ __launch_bounds__(256) void k_agg128b(const uint* __restrict__ XPb,
                                                 const int* __restrict__ rowptr,
                                                 const uint* __restrict__ sEdge,
                                                 const float* __restrict__ dinv,
                                                 const float* __restrict__ bias,
                                                 float* __restrict__ Y, int n) {
  AGG_PROLOGUE
  AGG_EDGE_LOOP
  AGG_FINISH(o0, o1, bias)
  ((float4*)(Y + (size_t)i * NF))[lane * 2] = o0;
  ((float4*)(Y + (size_t)i * NF))[lane * 2 + 1] = o1;
}

// layer-1 agg fused with W2 GEMV: writes only xp2[i]
__global__ __launch_bounds__(256) void k_agg_gemv(const uint* __restrict__ XPb,
                                                  const int* __restrict__ rowptr,
                                                  const uint* __restrict__ sEdge,
                                                  const float* __restrict__ dinv,
                                                  const float* __restrict__ bias,
                                                  const float* __restrict__ w2,
                                                  float* __restrict__ xp2, int n) {
  AGG_PROLOGUE
  AGG_EDGE_LOOP
  AGG_FINISH(o0, o1, bias)
  float4 wA = ((const float4*)w2)[lane * 2];
  float4 wB = ((const float4*)w2)[lane * 2 + 1];
  float sdot = o0.x * wA.x + o0.y * wA.y + o0.z * wA.z + o0.w * wA.w +
               o1.x * wB.x + o1.y * wB.y + o1.z * wB.z + o1.w * wB.w;
  sdot += __shfl_xor(sdot, 1, 64);
  sdot += __shfl_xor(sdot, 2, 64);
  sdot += __shfl_xor(sdot, 4, 64);
  sdot += __shfl_xor(sdot, 8, 64);
  if (lane == 0) xp2[i] = sdot;
}

// ---------------- layer 2: scalar aggregation ----------------

__global__ __launch_bounds__(256) void k_agg1(const float* __restrict__ xp2,
                                              const int* __restrict__ rowptr,
                                              const uint* __restrict__ sEdge,
                                              const float* __restrict__ dinv,
                                              const float* __restrict__ b2,
                                              float* __restrict__ out, int n) {
  int i = blockIdx.x * 256 + threadIdx.x;
  if (i >= n) return;
  float di = dinv[i];
  float accE = 0.0f;
  int s = rowptr[i], e = rowptr[i + 1];
  int j = s;
  for (; j + 4 <= e; j += 4) {
    uint e0 = sEdge[j], e1 = sEdge[j + 1], e2 = sEdge[j + 2], e3 = sEdge[j + 3];
    float v0 = xp2[e0 & 0x1FFFFu], v1 = xp2[e1 & 0x1FFFFu];
    float v2 = xp2[e2 & 0x1FFFFu], v3 = xp2[e3 & 0x1FFFFu];
    accE = fmaf(v0, (float)(e0 >> 17) * (1.0f / 32768.0f), accE);
    accE = fmaf(v1, (float)(e1 >> 17) * (1.0f / 32768.0f), accE);
    accE = fmaf(v2, (float)(e2 >> 17) * (1.0f / 32768.0f), accE);
    accE = fmaf(v3, (float)(e3 >> 17) * (1.0f / 32768.0f), accE);
  }
  for (; j < e; ++j) {
    uint e0 = sEdge[j];
    accE = fmaf(xp2[e0 & 0x1FFFFu], (float)(e0 >> 17) * (1.0f / 32768.0f), accE);
  }
  out[i] = fmaf(accE, di, fmaf(xp2[i], di * di, b2[0]));
}

// ---------------- launch ----------------

extern "C" void kernel_launch(void* const* d_in, const int* in_sizes, int n_in,
                              void* d_out, int out_size, void* d_ws, size_t ws_size,
                              hipStream_t stream) {
  const float* feat = (const float*)d_in[0];
  const int* ei = (const int*)d_in[1];
  const float* ew = (const float*)d_in[2];
  const float* W0 = (const float*)d_in[3];
  const float* b0 = (const float*)d_in[4];
  const float* W1 = (const float*)d_in[5];
  const float* b1 = (const float*)d_in[6];
  const float* W2 = (const float*)d_in[7];
  const float* b2 = (const float*)d_in[8];
  float* out = (float*)d_out;

  const int N_ = in_sizes[0] / NF;
  const int E_ = in_sizes[2];
  const int* row = ei;
  const int* col = ei + E_;

  char* ws = (char*)d_ws;
  size_t off = 0;
  auto alloc = [&](size_t bytes) -> void* {
    void* p = ws + off;
    off = (off + bytes + 255) & ~(size_t)255;
    return p;
  };
  float* bufA  = (float*)alloc((size_t)N_ * NF * 4);   // fp32 layer-0 activations
  uint*  bufBb = (uint*) alloc((size_t)N_ * NF * 2);   // bf16 GEMM outputs (XP)
  ull*   packed= (ull*)  alloc((size_t)N_ * 8);
  float* dinv  = (float*)alloc((size_t)N_ * 4);
  float* invs  = (float*)alloc((size_t)N_ * 4);
  int*   rowptr= (int*)  alloc(((size_t)N_ + 1) * 4);
  int*   bsum  = (int*)  alloc(256 * 4);
  int*   bexcl = (int*)  alloc(256 * 4);
  uint*  rank  = (uint*) alloc((size_t)E_ * 4);
  uint*  sEdge = (uint*) alloc((size_t)E_ * 4);
  float* xp2   = (float*)alloc((size_t)N_ * 4);

  const int nThreads = 256;
  const int gN   = (N_ + nThreads - 1) / nThreads;
  const int gE   = (E_ + nThreads - 1) / nThreads;
  const int gWav = (N_ + 3) / 4;               // one wave per node (rowsum)
  const int gAgg = (N_ + 15) / 16;             // 16 nodes per 256-thread block
  const int gGemm = (N_ + 63) / 64;
  const int nScanBlocks = (N_ + 1023) / 1024;  // <= 256 required

  hipMemsetAsync(packed, 0, (size_t)N_ * 8, stream);
  // K1: pass1 (atomics + rank) || rowsum
  k_pre1<<<gE + gWav, nThreads, 0, stream>>>(col, ew, packed, rank, E_, gE,
                                             feat, invs, N_);
  // scan (finish fused into scan_local)
  k_scan_local<<<nScanBlocks, nThreads, 0, stream>>>(packed, rowptr, bsum, dinv, N_);
  k_scan_sums<<<1, nThreads, 0, stream>>>(bsum, bexcl, rowptr + N_, nScanBlocks);
  k_scan_add<<<gN, nThreads, 0, stream>>>(rowptr, bexcl, N_);
  // K2: atomic-free scatter || layer-0 GEMM (64x64 blocks, 42KB LDS, 3 blk/CU)
  k_sc_gemm<<<gE + 2 * gGemm, nThreads, 0, stream>>>(row, col, ew, dinv, rowptr, rank,
                                                     sEdge, E_, gE,
                                                     feat, W0, invs, bufBb, N_);
  // layer 0 aggregation -> fp32 activations
  k_agg128b<<<gAgg, nThreads, 0, stream>>>(bufBb, rowptr, sEdge, dinv, b0, bufA, N_);
  // layer 1 GEMM
  k_gemm128<<<gGemm, nThreads, 0, stream>>>(bufA, W1, bufBb, N_);
  // layer 1 aggregation fused with W2 GEMV -> xp2 only
  k_agg_gemv<<<gAgg, nThreads, 0, stream>>>(bufBb, rowptr, sEdge, dinv, b1, W2, xp2, N_);
  // layer 2 aggregation
  k_agg1<<<gN, nThreads, 0, stream>>>(xp2, rowptr, sEdge, dinv, b2, out, N_);
}

// Round 14
// 427.445 us; speedup vs baseline: 2.0298x; 1.1200x over previous
//
#include <hip/hip_runtime.h>

#define NF 128
#define TILE_E 8192     // edges per coarse tile (256 thr x 32)
#define BKT_SHIFT 9
#define BKT_COLS 512    // cols per bucket; nB = ceil(N/512) <= 256 required
typedef unsigned long long ull;
typedef unsigned int uint;

// ---------------- bf16 helpers ----------------

__device__ __forceinline__ float bflo(uint u) { return __uint_as_float(u << 16); }
__device__ __forceinline__ float bfhi(uint u) { return __uint_as_float(u & 0xffff0000u); }
__device__ __forceinline__ uint pack_bf16(float a, float b) {  // RNE
  uint ua = __float_as_uint(a), ub = __float_as_uint(b);
  ua = (ua + 0x7fffu + ((ua >> 16) & 1u)) >> 16;
  ub = (ub + 0x7fffu + ((ub >> 16) & 1u)) & 0xffff0000u;
  return ua | ub;
}

// packed CSC edge entry: [31:17] = norm q15 fixed point, [16:0] = source row
__device__ __forceinline__ uint pack_edge(uint row, float nrm) {
  uint q = __float2uint_rn(nrm * 32768.0f);
  q = q > 32767u ? 32767u : q;
  return (q << 17) | row;
}

// ---- K1: coarse 256-bin histogram of col>>9 (LDS atomics) || rowsum --------

__global__ __launch_bounds__(256) void k_hist_rowsum(const int* __restrict__ col,
                                                     uint* __restrict__ hist,  // [256][nT]
                                                     int ne, int nT,
                                                     const float* __restrict__ feat,
                                                     float* __restrict__ invs, int n) {
  if ((int)blockIdx.x < nT) {
    __shared__ uint lh[256];
    int tid = threadIdx.x;
    lh[tid] = 0;
    __syncthreads();
    int base = blockIdx.x * TILE_E;
    int lim = min(ne - base, TILE_E);
    for (int k = tid; k < lim; k += 256) {
      int c = col[base + k];
      atomicAdd(&lh[c >> BKT_SHIFT], 1u);
    }
    __syncthreads();
    hist[(size_t)tid * nT + blockIdx.x] = lh[tid];
  } else {
    int gid = ((int)blockIdx.x - nT) * 256 + threadIdx.x;
    int wave = gid >> 6, lane = gid & 63;
    if (wave >= n) return;
    float2 v = ((const float2*)(feat + (size_t)wave * NF))[lane];
    float s = v.x + v.y;
    for (int off = 1; off < 64; off <<= 1) s += __shfl_xor(s, off, 64);
    if (lane == 0) invs[wave] = 1.0f / s;
  }
}

// ---- K2: per-bucket scan over tiles -> tile bases + bucket totals ----------

__global__ __launch_bounds__(256) void k_scan_tiles(const uint* __restrict__ hist,
                                                    uint* __restrict__ tbb,   // [nB][nT]
                                                    uint* __restrict__ btot, int nT) {
  __shared__ uint sd[256];
  int b = blockIdx.x, tid = threadIdx.x;
  uint v = (tid < nT) ? hist[(size_t)b * nT + tid] : 0u;
  sd[tid] = v;
  __syncthreads();
  for (int off = 1; off < 256; off <<= 1) {
    uint t = (tid >= off) ? sd[tid - off] : 0u;
    __syncthreads();
    sd[tid] += t;
    __syncthreads();
  }
  if (tid < nT) tbb[(size_t)b * nT + tid] = sd[tid] - v;
  if (tid == 255) btot[b] = sd[255];
}

// ---- K3: scan bucket totals -> bucket bases; rowptr[N] = E -----------------

__global__ __launch_bounds__(256) void k_scan_buckets(const uint* __restrict__ btot,
                                                      uint* __restrict__ bbase,
                                                      int* __restrict__ rowptrN,
                                                      int nB, int ne) {
  __shared__ uint sd[256];
  int tid = threadIdx.x;
  uint v = (tid < nB) ? btot[tid] : 0u;
  sd[tid] = v;
  __syncthreads();
  for (int off = 1; off < 256; off <<= 1) {
    uint t = (tid >= off) ? sd[tid - off] : 0u;
    __syncthreads();
    sd[tid] += t;
    __syncthreads();
  }
  if (tid < nB) bbase[tid] = sd[tid] - v;
  if (tid == nB - 1) bbase[nB] = sd[tid];  // == ne
  if (tid == 0) rowptrN[0] = ne;
}

// ---- K4: coarse scatter into bucket storage (LDS cursors, clustered writes)-

__global__ __launch_bounds__(256) void k_coarse(const int* __restrict__ row,
                                                const int* __restrict__ col,
                                                const float* __restrict__ w,
                                                const uint* __restrict__ tbb,
                                                const uint* __restrict__ bbase,
                                                uint2* __restrict__ bstore,
                                                int ne, int nT, int nB) {
  __shared__ uint cur[256];
  int t = blockIdx.x, tid = threadIdx.x;
  cur[tid] = (tid < nB) ? (bbase[tid] + tbb[(size_t)tid * nT + t]) : 0u;
  __syncthreads();
  int base = t * TILE_E;
  int lim = min(ne - base, TILE_E);
  for (int k = tid; k < lim; k += 256) {
    int e = base + k;
    int c = col[e];
    uint pos = atomicAdd(&cur[c >> BKT_SHIFT], 1u);
    bstore[pos] = make_uint2(((uint)(c & (BKT_COLS - 1)) << 17) | (uint)row[e],
                             __float_as_uint(w[e]));
  }
}

// ---- K5: fine pass per bucket: count + u24 degree, scan, emit CSC ----------

__global__ __launch_bounds__(256) void k_fine(const uint2* __restrict__ bstore,
                                              const uint* __restrict__ bbase,
                                              int* __restrict__ rowptr,
                                              float* __restrict__ dinv,
                                              uint* __restrict__ sEdge, int n) {
  __shared__ int hcnt[BKT_COLS];
  __shared__ int hws[BKT_COLS];
  __shared__ int cur[BKT_COLS];
  __shared__ int sd[256];
  int b = blockIdx.x, tid = threadIdx.x;
  int start = (int)bbase[b], end = (int)bbase[b + 1];
  hcnt[tid] = 0; hcnt[tid + 256] = 0;
  hws[tid] = 0;  hws[tid + 256] = 0;
  __syncthreads();
  for (int i = start + tid; i < end; i += 256) {
    uint2 v = bstore[i];
    int cl = (int)(v.x >> 17);
    atomicAdd(&hcnt[cl], 1);
    int wf = (int)__float2uint_rn(__uint_as_float(v.y) * 16777216.0f);  // w * 2^24
    atomicAdd(&hws[cl], wf);
  }
  __syncthreads();
  // exclusive scan of hcnt[512]; thread tid owns elements 2t, 2t+1
  int a0 = hcnt[2 * tid], a1 = hcnt[2 * tid + 1];
  int ps = a0 + a1;
  sd[tid] = ps;
  __syncthreads();
  for (int off = 1; off < 256; off <<= 1) {
    int tv = (tid >= off) ? sd[tid - off] : 0;
    __syncthreads();
    sd[tid] += tv;
    __syncthreads();
  }
  int pexcl = sd[tid] - ps;
  cur[2 * tid] = pexcl;
  cur[2 * tid + 1] = pexcl + a0;
  {
    const float k24 = 1.0f / 16777216.0f;
    int c0 = b * BKT_COLS + 2 * tid;
    if (c0 < n) {
      rowptr[c0] = start + pexcl;
      dinv[c0] = rsqrtf((float)hws[2 * tid] * k24 + 1.0f);  // +1 self loop
    }
    if (c0 + 1 < n) {
      rowptr[c0 + 1] = start + pexcl + a0;
      dinv[c0 + 1] = rsqrtf((float)hws[2 * tid + 1] * k24 + 1.0f);
    }
  }
  __syncthreads();
  for (int i = start + tid; i < end; i += 256) {
    uint2 v = bstore[i];
    int cl = (int)(v.x >> 17);
    int pos = start + atomicAdd(&cur[cl], 1);
    float wv = __uint_as_float(v.y);
    uint wq = __float2uint_rn(wv * 32768.0f);
    wq = wq > 32767u ? 32767u : wq;
    sEdge[pos] = (wq << 17) | (v.x & 0x1FFFFu);  // (w q15, row) pre-norm
  }
}

// ---- K6: fixup norm in place: (w,row) -> (dinv[row]*w, row) ----------------
// dinv is 400KB -> L2-resident; random READS are cheap (unlike stores).

__global__ __launch_bounds__(256) void k_fix(uint* __restrict__ sEdge,
                                             const float* __restrict__ dinv, int ne) {
  int i = blockIdx.x * 256 + threadIdx.x;
  if (i >= ne) return;
  uint en = sEdge[i];
  uint r = en & 0x1FFFFu;
  float wv = (float)(en >> 17) * (1.0f / 32768.0f);
  sEdge[i] = pack_edge(r, dinv[r] * wv);
}

// ------- GEMM: Yb[n,128](bf16) = diag(scale) X[n,128] @ W[128,128] ----------

__global__ __launch_bounds__(256, 2) void k_gemm128(const float* __restrict__ X,
                                                    const float* __restrict__ W,
                                                    uint* __restrict__ Yb, int n,
                                                    const float* __restrict__ scale) {
  __shared__ float Ws[128 * 128];
  __shared__ float Xs[64 * 36];
  const int tid = threadIdx.x;
  for (int i = tid * 4; i < 128 * 128; i += 256 * 4)
    *(float4*)&Ws[i] = *(const float4*)&W[i];

  int r0 = blockIdx.x * 64;
  int tcol = tid & 15, trow = tid >> 4;
  float acc[4][8] = {};

  for (int kc = 0; kc < 128; kc += 32) {
    __syncthreads();
    {
      int rr = tid >> 2;
      int cc = (tid & 3) * 8;
      int grow = r0 + rr;
      if (grow >= n) grow = n - 1;
      float sc = scale ? scale[grow] : 1.0f;
      const float* src = X + (size_t)grow * NF + kc + cc;
      float4 a = *(const float4*)src;
      float4 b = *(const float4*)(src + 4);
      a.x *= sc; a.y *= sc; a.z *= sc; a.w *= sc;
      b.x *= sc; b.y *= sc; b.z *= sc; b.w *= sc;
      *(float4*)&Xs[rr * 36 + cc] = a;
      *(float4*)&Xs[rr * 36 + cc + 4] = b;
    }
    __syncthreads();
#pragma unroll
    for (int k4 = 0; k4 < 32; k4 += 4) {
      float4 xv[4];
#pragma unroll
      for (int i = 0; i < 4; i++)
        xv[i] = *(const float4*)&Xs[(trow * 4 + i) * 36 + k4];
#pragma unroll
      for (int kk = 0; kk < 4; kk++) {
        float4 w0 = *(const float4*)&Ws[(kc + k4 + kk) * 128 + tcol * 4];
        float4 w1 = *(const float4*)&Ws[(kc + k4 + kk) * 128 + 64 + tcol * 4];
#pragma unroll
        for (int i = 0; i < 4; i++) {
          float xx = ((const float*)&xv[i])[kk];
          acc[i][0] = fmaf(xx, w0.x, acc[i][0]);
          acc[i][1] = fmaf(xx, w0.y, acc[i][1]);
          acc[i][2] = fmaf(xx, w0.z, acc[i][2]);
          acc[i][3] = fmaf(xx, w0.w, acc[i][3]);
          acc[i][4] = fmaf(xx, w1.x, acc[i][4]);
          acc[i][5] = fmaf(xx, w1.y, acc[i][5]);
          acc[i][6] = fmaf(xx, w1.z, acc[i][6]);
          acc[i][7] = fmaf(xx, w1.w, acc[i][7]);
        }
      }
    }
  }
#pragma unroll
  for (int i = 0; i < 4; i++) {
    int gr = r0 + trow * 4 + i;
    if (gr < n) {
      uint2 p0 = {pack_bf16(acc[i][0], acc[i][1]), pack_bf16(acc[i][2], acc[i][3])};
      uint2 p1 = {pack_bf16(acc[i][4], acc[i][5]), pack_bf16(acc[i][6], acc[i][7])};
      *(uint2*)&Yb[(size_t)gr * 64 + tcol * 2] = p0;
      *(uint2*)&Yb[(size_t)gr * 64 + 32 + tcol * 2] = p1;
    }
  }
}

// ---------------- pull aggregation, H=128, bf16 gathers ----------------

#define AGG_PROLOGUE \
  int gid = blockIdx.x * 256 + threadIdx.x; \
  int i = gid >> 4; \
  int lane = gid & 15; \
  if (i >= n) return; \
  float di = dinv[i]; \
  uint4 xv = ((const uint4*)XPb)[(size_t)i * 16 + lane]; \
  int s = rowptr[i], e = rowptr[i + 1]; \
  float acc[8] = {0.f, 0.f, 0.f, 0.f, 0.f, 0.f, 0.f, 0.f}; \
  int j = s;

#define GATHER(en, g) \
  uint4 g = ((const uint4*)XPb)[(size_t)((en) & 0x1FFFFu) * 16 + lane];
#define ACCUM(en, g) { \
  float nr = (float)((en) >> 17) * (1.0f / 32768.0f); \
  acc[0] = fmaf(bflo(g.x), nr, acc[0]); acc[1] = fmaf(bfhi(g.x), nr, acc[1]); \
  acc[2] = fmaf(bflo(g.y), nr, acc[2]); acc[3] = fmaf(bfhi(g.y), nr, acc[3]); \
  acc[4] = fmaf(bflo(g.z), nr, acc[4]); acc[5] = fmaf(bfhi(g.z), nr, acc[5]); \
  acc[6] = fmaf(bflo(g.w), nr, acc[6]); acc[7] = fmaf(bfhi(g.w), nr, acc[7]); }

#define AGG_EDGE_LOOP \
  for (; j + 8 <= e; j += 8) { \
    uint e0 = sEdge[j],     e1 = sEdge[j + 1], e2 = sEdge[j + 2], e3 = sEdge[j + 3]; \
    uint e4 = sEdge[j + 4], e5 = sEdge[j + 5], e6 = sEdge[j + 6], e7 = sEdge[j + 7]; \
    GATHER(e0, g0) GATHER(e1, g1) GATHER(e2, g2) GATHER(e3, g3) \
    GATHER(e4, g4) GATHER(e5, g5) GATHER(e6, g6) GATHER(e7, g7) \
    ACCUM(e0, g0) ACCUM(e1, g1) ACCUM(e2, g2) ACCUM(e3, g3) \
    ACCUM(e4, g4) ACCUM(e5, g5) ACCUM(e6, g6) ACCUM(e7, g7) \
  } \
  if (j + 4 <= e) { \
    uint e0 = sEdge[j], e1 = sEdge[j + 1], e2 = sEdge[j + 2], e3 = sEdge[j + 3]; \
    GATHER(e0, g0) GATHER(e1, g1) GATHER(e2, g2) GATHER(e3, g3) \
    ACCUM(e0, g0) ACCUM(e1, g1) ACCUM(e2, g2) ACCUM(e3, g3) \
    j += 4; \
  } \
  for (; j < e; ++j) { \
    uint e0 = sEdge[j]; \
    GATHER(e0, g0) \
    ACCUM(e0, g0) \
  }

#define AGG_FINISH(o0, o1, bias) \
  float sn = di * di; \
  float4 o0, o1; \
  { \
    float4 bA = ((const float4*)bias)[lane * 2]; \
    float4 bB = ((const float4*)bias)[lane * 2 + 1]; \
    o0.x = fmaf(acc[0], di, fmaf(bflo(xv.x), sn, bA.x)); \
    o0.y = fmaf(acc[1], di, fmaf(bfhi(xv.x), sn, bA.y)); \
    o0.z = fmaf(acc[2], di, fmaf(bflo(xv.y), sn, bA.z)); \
    o0.w = fmaf(acc[3], di, fmaf(bfhi(xv.y), sn, bA.w)); \
    o1.x = fmaf(acc[4], di, fmaf(bflo(xv.z), sn, bB.x)); \
    o1.y = fmaf(acc[5], di, fmaf(bfhi(xv.z), sn, bB.y)); \
    o1.z = fmaf(acc[6], di, fmaf(bflo(xv.w), sn, bB.z)); \
    o1.w = fmaf(acc[7], di, fmaf(bfhi(xv.w), sn, bB.w)); \
    o0.x = fmaxf(o0.x, 0.f); o0.y = fmaxf(o0.y, 0.f); \
    o0.z = fmaxf(o0.z, 0.f); o0.w = fmaxf(o0.w, 0.f); \
    o1.x = fmaxf(o1.x, 0.f); o1.y = fmaxf(o1.y, 0.f); \
    o1.z = fmaxf(o1.z, 0.f); o1.w = fmaxf(o1.w, 0.f); \
  }

// layer-0 agg: writes fp32 activations (relu)
__global__ __launch_bounds__(256) void k_agg128b(const uint* __restrict__ XPb,
                                                 const int* __restrict__ rowptr,
                                                 const uint* __restrict__ sEdge,
                                                 const float* __restrict__ dinv,
                                                 const float* __restrict__ bias,
                                                 float* __restrict__ Y, int n) {
  AGG_PROLOGUE
  AGG_EDGE_LOOP
  AGG_FINISH(o0, o1, bias)
  ((float4*)(Y + (size_t)i * NF))[lane * 2] = o0;
  ((float4*)(Y + (size_t)i * NF))[lane * 2 + 1] = o1;
}

// layer-1 agg fused with W2 GEMV: writes only xp2[i]
__global__ __launch_bounds__(256) void k_agg_gemv(const uint* __restrict__ XPb,
                                                  const int* __restrict__ rowptr,
                                                  const uint* __restrict__ sEdge,
                                                  const float* __restrict__ dinv,
                                                  const float* __restrict__ bias,
                                                  const float* __restrict__ w2,
                                                  float* __restrict__ xp2, int n) {
  AGG_PROLOGUE
  AGG_EDGE_LOOP
  AGG_FINISH(o0, o1, bias)
  float4 wA = ((const float4*)w2)[lane * 2];
  float4 wB = ((const float4*)w2)[lane * 2 + 1];
  float sdot = o0.x * wA.x + o0.y * wA.y + o0.z * wA.z + o0.w * wA.w +
               o1.x * wB.x + o1.y * wB.y + o1.z * wB.z + o1.w * wB.w;
  sdot += __shfl_xor(sdot, 1, 64);
  sdot += __shfl_xor(sdot, 2, 64);
  sdot += __shfl_xor(sdot, 4, 64);
  sdot += __shfl_xor(sdot, 8, 64);
  if (lane == 0) xp2[i] = sdot;
}

// ---------------- layer 2: scalar aggregation ----------------

__global__ __launch_bounds__(256) void k_agg1(const float* __restrict__ xp2,
                                              const int* __restrict__ rowptr,
                                              const uint* __restrict__ sEdge,
                                              const float* __restrict__ dinv,
                                              const float* __restrict__ b2,
                                              float* __restrict__ out, int n) {
  int i = blockIdx.x * 256 + threadIdx.x;
  if (i >= n) return;
  float di = dinv[i];
  float accE = 0.0f;
  int s = rowptr[i], e = rowptr[i + 1];
  int j = s;
  for (; j + 4 <= e; j += 4) {
    uint e0 = sEdge[j], e1 = sEdge[j + 1], e2 = sEdge[j + 2], e3 = sEdge[j + 3];
    float v0 = xp2[e0 & 0x1FFFFu], v1 = xp2[e1 & 0x1FFFFu];
    float v2 = xp2[e2 & 0x1FFFFu], v3 = xp2[e3 & 0x1FFFFu];
    accE = fmaf(v0, (float)(e0 >> 17) * (1.0f / 32768.0f), accE);
    accE = fmaf(v1, (float)(e1 >> 17) * (1.0f / 32768.0f), accE);
    accE = fmaf(v2, (float)(e2 >> 17) * (1.0f / 32768.0f), accE);
    accE = fmaf(v3, (float)(e3 >> 17) * (1.0f / 32768.0f), accE);
  }
  for (; j < e; ++j) {
    uint e0 = sEdge[j];
    accE = fmaf(xp2[e0 & 0x1FFFFu], (float)(e0 >> 17) * (1.0f / 32768.0f), accE);
  }
  out[i] = fmaf(accE, di, fmaf(xp2[i], di * di, b2[0]));
}

// ---------------- launch ----------------

extern "C" void kernel_launch(void* const* d_in, const int* in_sizes, int n_in,
                              void* d_out, int out_size, void* d_ws, size_t ws_size,
                              hipStream_t stream) {
  const float* feat = (const float*)d_in[0];
  const int* ei = (const int*)d_in[1];
  const float* ew = (const float*)d_in[2];
  const float* W0 = (const float*)d_in[3];
  const float* b0 = (const float*)d_in[4];
  const float* W1 = (const float*)d_in[5];
  const float* b1 = (const float*)d_in[6];
  const float* W2 = (const float*)d_in[7];
  const float* b2 = (const float*)d_in[8];
  float* out = (float*)d_out;

  const int N_ = in_sizes[0] / NF;
  const int E_ = in_sizes[2];
  const int* row = ei;
  const int* col = ei + E_;

  char* ws = (char*)d_ws;
  size_t off = 0;
  auto alloc = [&](size_t bytes) -> void* {
    void* p = ws + off;
    off = (off + bytes + 255) & ~(size_t)255;
    return p;
  };
  const int nT = (E_ + TILE_E - 1) / TILE_E;          // coarse tiles (<=256)
  const int nB = (N_ + BKT_COLS - 1) / BKT_COLS;      // buckets (<=256)

  float* bufA  = (float*)alloc((size_t)N_ * NF * 4);  // fp32 layer-0 activations
  uint*  bufBb = (uint*) alloc((size_t)N_ * NF * 2);  // bf16 GEMM outputs (XP)
  uint2* bstore= (uint2*)alloc((size_t)E_ * 8);       // coarse-bucketed edges
  uint*  sEdge = (uint*) alloc((size_t)E_ * 4);
  uint*  hist  = (uint*) alloc((size_t)256 * nT * 4); // [256][nT]
  uint*  tbb   = (uint*) alloc((size_t)256 * nT * 4); // [nB][nT]
  uint*  btot  = (uint*) alloc(256 * 4);
  uint*  bbase = (uint*) alloc(257 * 4);
  float* dinv  = (float*)alloc((size_t)N_ * 4);
  float* invs  = (float*)alloc((size_t)N_ * 4);
  int*   rowptr= (int*)  alloc(((size_t)N_ + 1) * 4);
  float* xp2   = (float*)alloc((size_t)N_ * 4);

  const int nThreads = 256;
  const int gN   = (N_ + nThreads - 1) / nThreads;
  const int gE   = (E_ + nThreads - 1) / nThreads;
  const int gWav = (N_ + 3) / 4;               // one wave per node (rowsum)
  const int gAgg = (N_ + 15) / 16;             // 16 nodes per 256-thread block
  const int gGemm = (N_ + 63) / 64;

  // CSC build: coarse hist -> scans -> coarse scatter -> fine pass -> fixup.
  // No global atomics, no wide random stores (R9/R11 lesson: those are
  // transaction-bound at ~21 ops/ns and fusion can't hide them).
  k_hist_rowsum<<<nT + gWav, nThreads, 0, stream>>>(col, hist, E_, nT, feat, invs, N_);
  k_scan_tiles<<<nB, nThreads, 0, stream>>>(hist, tbb, btot, nT);
  k_scan_buckets<<<1, nThreads, 0, stream>>>(btot, bbase, rowptr + N_, nB, E_);
  k_coarse<<<nT, nThreads, 0, stream>>>(row, col, ew, tbb, bbase, bstore, E_, nT, nB);
  k_fine<<<nB, nThreads, 0, stream>>>(bstore, bbase, rowptr, dinv, sEdge, N_);
  k_fix<<<gE, nThreads, 0, stream>>>(sEdge, dinv, E_);

  // layer 0 (row-normalization folded into GEMM via invs; bf16 XP out)
  k_gemm128<<<gGemm, nThreads, 0, stream>>>(feat, W0, bufBb, N_, invs);
  k_agg128b<<<gAgg, nThreads, 0, stream>>>(bufBb, rowptr, sEdge, dinv, b0, bufA, N_);
  // layer 1
  k_gemm128<<<gGemm, nThreads, 0, stream>>>(bufA, W1, bufBb, N_, nullptr);
  k_agg_gemv<<<gAgg, nThreads, 0, stream>>>(bufBb, rowptr, sEdge, dinv, b1, W2, xp2, N_);
  // layer 2
  k_agg1<<<gN, nThreads, 0, stream>>>(xp2, rowptr, sEdge, dinv, b2, out, N_);
}